// Round 5
// baseline (1632.474 us; speedup 1.0000x reference)
//
#include <hip/hip_runtime.h>

typedef __attribute__((ext_vector_type(8))) short bf16x8;
typedef __attribute__((ext_vector_type(4))) float f32x4;
typedef __attribute__((ext_vector_type(4))) ushort u16x4;

__device__ __forceinline__ ushort f2b(float v) {
    union { float f; unsigned u; } x; x.f = v;
    unsigned r = x.u + 0x7fffu + ((x.u >> 16) & 1u);
    return (ushort)(r >> 16);
}
__device__ __forceinline__ float b2f(ushort b) {
    union { float f; unsigned u; } x; x.u = ((unsigned)b) << 16; return x.f;
}

// async global->LDS 16B per lane; LDS dest = wave-uniform base + lane*16
__device__ __forceinline__ void gl_lds16(const void* g, void* l) {
    __builtin_amdgcn_global_load_lds(
        (__attribute__((address_space(1))) void*)(g),
        (__attribute__((address_space(3))) void*)(l), 16, 0, 0);
}

// ---------------- prep kernels ----------------

__global__ void k_split(const float* __restrict__ src, ushort* __restrict__ hi,
                        ushort* __restrict__ lo, int rows, int K, int Kpad) {
    long total = (long)rows * Kpad;
    for (long idx = (long)blockIdx.x * 256 + threadIdx.x; idx < total;
         idx += (long)gridDim.x * 256) {
        int r = (int)(idx / Kpad), c = (int)(idx % Kpad);
        float v = (c < K) ? src[(long)r * K + c] : 0.f;
        ushort h = f2b(v);
        hi[idx] = h;
        if (lo) lo[idx] = f2b(v - b2f(h));
    }
}

// W2 prepack for K-partial GEMM2 B-frags.
// idx bits: w(2)|p(2)|n2(3)|hi(2)|lo(4)|e(3); d2 = n2*16+lo;
// hcol = (p*2 + (e>>2))*64 + w*16 + hi*4 + (e&3)
__global__ void k_w2p(const float* __restrict__ W2, ushort* __restrict__ W2p) {
    int idx = blockIdx.x * 256 + threadIdx.x;
    if (idx >= 65536) return;
    int e = idx & 7, lo = (idx >> 3) & 15, hi = (idx >> 7) & 3;
    int n2 = (idx >> 9) & 7, p = (idx >> 12) & 3, w = (idx >> 14) & 3;
    int d2 = n2 * 16 + lo;
    int hcol = (p * 2 + (e >> 2)) * 64 + w * 16 + hi * 4 + (e & 3);
    W2p[idx] = f2b(W2[d2 * 512 + hcol]);
}

// Wc[n][k] = sum_d qkvW[n][d] * fl1W[d][k];  bc[n] = sum_d qkvW[n][d] * fl1b[d]
__global__ void k_wc(const float* __restrict__ qkvW, const float* __restrict__ fl1W,
                     const float* __restrict__ fl1b, float* __restrict__ Wc,
                     float* __restrict__ bc) {
    int idx = blockIdx.x * 256 + threadIdx.x;
    if (idx >= 384 * 1024) return;
    int n = idx >> 10, k = idx & 1023;
    float s = 0.f;
    #pragma unroll 8
    for (int d = 0; d < 128; ++d) s += qkvW[n * 128 + d] * fl1W[d * 1024 + k];
    Wc[idx] = s;
    if (k == 0) {
        float sb = 0.f;
        #pragma unroll 8
        for (int d = 0; d < 128; ++d) sb += qkvW[n * 128 + d] * fl1b[d];
        bc[n] = sb;
    }
}

__global__ void k_sk(const float* __restrict__ fs, const float* __restrict__ fW,
                     const float* __restrict__ fb, float* __restrict__ sk) {
    int m = blockIdx.x * 256 + threadIdx.x;
    if (m >= 12800) return;
    int b = m / 50, i = m % 50;
    float s = fb[i];
    #pragma unroll 4
    for (int c = 0; c < 36; ++c) s += fs[b * 36 + c] * fW[i * 36 + c];
    sk[m] = s;
}

// GRU(10->10): one wave (=one block of 64) per batch element -> 256 CUs covered
__global__ void k_gru(const float* __restrict__ noise, const float* __restrict__ Wih,
                      const float* __restrict__ Whh, const float* __restrict__ bih,
                      const float* __restrict__ bhh, float* __restrict__ aux) {
    int lane = threadIdx.x & 63;
    int b = blockIdx.x;
    if (b >= 256) return;
    float wih[10] = {}, whh[10] = {};
    float bi = 0.f, bh = 0.f;
    if (lane < 30) {
        #pragma unroll
        for (int c = 0; c < 10; ++c) { wih[c] = Wih[lane * 10 + c]; whh[c] = Whh[lane * 10 + c]; }
        bi = bih[lane]; bh = bhh[lane];
    }
    float h = 0.f;
    for (int t = 0; t < 50; ++t) {
        float xr = (lane < 10) ? noise[(b * 50 + t) * 10 + lane] : 0.f;
        float gi = bi, gh = bh;
        #pragma unroll
        for (int c = 0; c < 10; ++c) {
            float xc = __shfl(xr, c, 64);
            float hc = __shfl(h, c, 64);
            gi += wih[c] * xc; gh += whh[c] * hc;
        }
        float siz = __shfl(gi, lane + 10, 64), shz = __shfl(gh, lane + 10, 64);
        float sin_ = __shfl(gi, lane + 20, 64), shn = __shfl(gh, lane + 20, 64);
        float r = 1.f / (1.f + expf(-(gi + gh)));
        float z = 1.f / (1.f + expf(-(siz + shz)));
        float n = tanhf(sin_ + r * shn);
        float hn = (1.f - z) * n + z * h;
        if (lane < 10) { h = hn; aux[(b * 50 + t) * 10 + lane] = tanhf(hn); }
    }
}

__global__ void k_xbuild(const float* __restrict__ input, const float* __restrict__ aux,
                         const float* __restrict__ sk, ushort* __restrict__ xhi,
                         ushort* __restrict__ xlo, long M) {
    long idx = (long)blockIdx.x * 256 + threadIdx.x;
    if (idx >= M * 288) return;
    int m = (int)(idx / 288), c = (int)(idx % 288);
    float v;
    if (c < 256) v = input[(long)m * 256 + c];
    else if (c < 266) v = aux[m * 10 + (c - 256)];
    else if (c == 266) v = sk[m];
    else v = 0.f;
    ushort h = f2b(v);
    xhi[idx] = h;
    xlo[idx] = f2b(v - b2f(h));
}

// ---------------- split-bf16 MFMA GEMM, global_load_lds staging ----------------
// XCD-aware bijective remap (m204): each XCD gets a contiguous wgid range,
// ordered x-fast/y-slow so its B working set stays L2-resident and each
// A-tile is reused by consecutive same-XCD blocks.
template <int MODE>
__global__ __launch_bounds__(256, 3) void k_gemm(
    const ushort* __restrict__ Ahi, const ushort* __restrict__ Alo,
    const ushort* __restrict__ Bhi, const ushort* __restrict__ Blo,
    int N, int K,
    float* outF, ushort* outHi, ushort* outLo,
    const float* __restrict__ bias,
    const float* __restrict__ bng, const float* __restrict__ bnb,
    const float* __restrict__ bnm, const float* __restrict__ bnv,
    const ushort* resHi, const ushort* resLo) {
    __shared__ __align__(16) ushort S[4][128][32];   // Ah, Al, Bh, Bl : 32 KB
    int t = threadIdx.x;
    // XCD swizzle
    int flat = blockIdx.y * gridDim.x + blockIdx.x;
    int nwg = gridDim.x * gridDim.y;
    int q = nwg >> 3, r = nwg & 7;
    int xcd = flat & 7, seq = flat >> 3;
    int wgid = (xcd < r ? xcd * (q + 1) : r * (q + 1) + (xcd - r) * q) + seq;
    int bx = wgid % gridDim.x, by = wgid / gridDim.x;
    int m0 = by * 128, n0 = bx * 128;
    int w = t >> 6, lane = t & 63;
    int wm = w >> 1, wn = w & 1;
    int lo16 = lane & 15, hi4 = lane >> 4;

    const int srow = lane >> 2;
    const int skoff = ((lane & 3) ^ (srow & 3)) * 8;   // elements
    const int slot8 = (hi4 ^ (lo16 & 3)) * 8;

    f32x4 acc[4][4];
    #pragma unroll
    for (int i = 0; i < 4; ++i)
        #pragma unroll
        for (int j = 0; j < 4; ++j) acc[i][j] = f32x4{0.f, 0.f, 0.f, 0.f};

    const int nk = K / 32;
    for (int kt = 0; kt < nk; ++kt) {
        const int kb = kt * 32;
        #pragma unroll
        for (int i = 0; i < 2; ++i) {
            int rg = w * 32 + i * 16;              // wave-uniform row-group base
            long ga = (long)(m0 + rg + srow) * K + kb + skoff;
            long gb = (long)(n0 + rg + srow) * K + kb + skoff;
            gl_lds16(&Ahi[ga], &S[0][rg][0]);
            gl_lds16(&Alo[ga], &S[1][rg][0]);
            gl_lds16(&Bhi[gb], &S[2][rg][0]);
            gl_lds16(&Blo[gb], &S[3][rg][0]);
        }
        __syncthreads();
        bf16x8 ah[4], al[4], bh[4], bl[4];
        #pragma unroll
        for (int m = 0; m < 4; ++m) {
            int row = wm * 64 + m * 16 + lo16;
            ah[m] = *(const bf16x8*)&S[0][row][slot8];
            al[m] = *(const bf16x8*)&S[1][row][slot8];
        }
        #pragma unroll
        for (int n = 0; n < 4; ++n) {
            int col = wn * 64 + n * 16 + lo16;
            bh[n] = *(const bf16x8*)&S[2][col][slot8];
            bl[n] = *(const bf16x8*)&S[3][col][slot8];
        }
        #pragma unroll
        for (int m = 0; m < 4; ++m)
            #pragma unroll
            for (int n = 0; n < 4; ++n) {
                acc[m][n] = __builtin_amdgcn_mfma_f32_16x16x32_bf16(ah[m], bh[n], acc[m][n], 0, 0, 0);
                acc[m][n] = __builtin_amdgcn_mfma_f32_16x16x32_bf16(ah[m], bl[n], acc[m][n], 0, 0, 0);
                acc[m][n] = __builtin_amdgcn_mfma_f32_16x16x32_bf16(al[m], bh[n], acc[m][n], 0, 0, 0);
            }
        __syncthreads();
    }

    #pragma unroll
    for (int n = 0; n < 4; ++n) {
        int gn = n0 + wn * 64 + n * 16 + lo16;
        float bv = bias ? bias[gn] : 0.f;
        float sc = 1.f, sh = 0.f;
        if (MODE >= 1) { sc = bng[gn] * rsqrtf(bnv[gn] + 1e-5f); sh = bnb[gn] - bnm[gn] * sc; }
        #pragma unroll
        for (int m = 0; m < 4; ++m)
            #pragma unroll
            for (int r2 = 0; r2 < 4; ++r2) {
                int gm = m0 + wm * 64 + m * 16 + hi4 * 4 + r2;
                long o = (long)gm * N + gn;
                float v = acc[m][n][r2] + bv;
                if (MODE >= 1) v = fmaxf(v * sc + sh, 0.f);
                if (MODE == 2) v += b2f(resHi[o]) + b2f(resLo[o]);
                if (outF) outF[o] = v;
                if (outHi) {
                    ushort hb = f2b(v);
                    outHi[o] = hb;
                    outLo[o] = f2b(v - b2f(hb));
                }
            }
    }
}

// ---------------- pos (fl2): wave-per-row, vectorized hi/lo loads ----------------
__global__ void k_fl2(const ushort* __restrict__ hA, const ushort* __restrict__ lA,
                      const float* __restrict__ W, const float* __restrict__ bias,
                      float* __restrict__ pos) {
    int w = threadIdx.x >> 6, lane = threadIdx.x & 63;
    int m = blockIdx.x * 4 + w;
    float a0 = 0.f, a1 = 0.f, a2 = 0.f;
    for (int k0 = lane * 4; k0 < 1024; k0 += 256) {
        long o = (long)m * 1024 + k0;
        u16x4 hv = *(const u16x4*)&hA[o];
        u16x4 lv = *(const u16x4*)&lA[o];
        f32x4 w0 = *(const f32x4*)&W[k0];
        f32x4 w1 = *(const f32x4*)&W[1024 + k0];
        f32x4 w2 = *(const f32x4*)&W[2048 + k0];
        #pragma unroll
        for (int e = 0; e < 4; ++e) {
            float x = b2f(hv[e]) + b2f(lv[e]);
            a0 += x * w0[e]; a1 += x * w1[e]; a2 += x * w2[e];
        }
    }
    #pragma unroll
    for (int off = 32; off; off >>= 1) {
        a0 += __shfl_xor(a0, off, 64);
        a1 += __shfl_xor(a1, off, 64);
        a2 += __shfl_xor(a2, off, 64);
    }
    if (lane == 0) {
        pos[m * 3 + 0] = a0 + bias[0];
        pos[m * 3 + 1] = a1 + bias[1];
        pos[m * 3 + 2] = a2 + bias[2];
    }
}

// ---------------- fused attention (+rel_emb +fl3) per (b,i) block ----------------
// R10: barrier-free main loop via swapped-operand GEMM1 + K-partial GEMM2.
// GEMM1 computes H^T = W1 . X^T  (mfma(w1frag, xsfrag)): C-layout puts j in
// lane&15 == exactly GEMM2's A-row layout, so H never round-trips through LDS.
// Wave w owns hcols {e8*64 + w*16 .. +16} per e8; per e8-PAIR it packs its
// K=32 H-chunk (bias+relu+f2b, k-order (hi4, e8sel, r) matching k_w2p) and
// accumulates GEMM2 partials over ALL 128 d2 -> acc2[4][8] = 128 AGPR.
// launch_bounds(256,2): 256-reg unified budget (est. peak ~235, no spill).
// All acc2 indices compile-time literal (rule #20). Main loop: ZERO barriers.
// Epilogue: own-slice extraction + 4-round LDS cross-wave reduce (8 barriers,
// lane-stride conflict-free), then R0's verbatim softmax/agg/fl3 tail on own[].
// LDS map (64KB -> 2 blocks/CU):
//   [0,16384)      REL[64][256B pitch], swz byte = j*256 + ((d*2)^((j&15)<<4))
//   [16384,32768)  XS[64][256B pitch] (A-source all main loop), same swz
//   [32768,65536)  reduce buf: 4 x 8KB wave regions [idx f32 x 64 lanes];
//                  aggF f32[128] overlaid at 32768 after final reduce barrier.
__global__ __launch_bounds__(256, 2) void k_attn(
    const float* __restrict__ qkv, const float* __restrict__ posb,
    const ushort* __restrict__ W1b, const ushort* __restrict__ W2p,
    const float* __restrict__ b1, const ushort* __restrict__ pW2b,
    const float* __restrict__ pW1, const float* __restrict__ pb1,
    const float* __restrict__ pb2,
    const float* __restrict__ fl3W, const float* __restrict__ fl3b,
    float* __restrict__ out, long mbase) {
    __shared__ __align__(16) char smem[65536];
    // XCD-aware swizzle: gridDim.x % 8 == 0 always (12800 or 6400)
    int cpx = gridDim.x >> 3;
    int biL = (blockIdx.x & 7) * cpx + (blockIdx.x >> 3);
    int bL = biL / 50;
    int t = threadIdx.x, w = t >> 6, lane = t & 63;
    int lo16 = lane & 15, hi4 = lane >> 4;

    // ---- phase 0a: h1 fragments in registers (row-split, wave-private) ----
    bf16x8 h_a[2];
    {
        const int jrow = w * 16 + lo16;
        const bool jvalid = jrow < 50;
        float pi0 = posb[biL * 3], pi1 = posb[biL * 3 + 1], pi2 = posb[biL * 3 + 2];
        float d0 = 0.f, d1 = 0.f, d2 = 0.f;
        if (jvalid) {
            int pj = (bL * 50 + jrow) * 3;
            d0 = pi0 - posb[pj]; d1 = pi1 - posb[pj + 1]; d2 = pi2 - posb[pj + 2];
        }
        #pragma unroll
        for (int kt = 0; kt < 2; ++kt)
            #pragma unroll
            for (int e = 0; e < 8; ++e) {
                int ke = kt * 32 + hi4 * 8 + e;
                float v = 0.f;
                if (jvalid)
                    v = fmaxf(pb1[ke] + pW1[ke * 3] * d0 + pW1[ke * 3 + 1] * d1
                              + pW1[ke * 3 + 2] * d2, 0.f);
                h_a[kt][e] = (short)f2b(v);
            }
    }

    // ---- phase 0b: rel rows for own 16 j (MFMA K=64) -> REL (wave-private) ----
    {
        f32x4 racc[8];
        #pragma unroll
        for (int n = 0; n < 8; ++n) racc[n] = f32x4{0.f, 0.f, 0.f, 0.f};
        #pragma unroll
        for (int kt = 0; kt < 2; ++kt) {
            int k0 = kt * 32 + hi4 * 8;
            #pragma unroll
            for (int n = 0; n < 8; ++n) {
                bf16x8 bv = *(const bf16x8*)&pW2b[(n * 16 + lo16) * 64 + k0];
                racc[n] = __builtin_amdgcn_mfma_f32_16x16x32_bf16(h_a[kt], bv, racc[n], 0, 0, 0);
            }
        }
        #pragma unroll
        for (int n = 0; n < 8; ++n) {
            int col = n * 16 + lo16;
            float pb = pb2[col];
            #pragma unroll
            for (int r = 0; r < 4; ++r) {
                int j = w * 16 + hi4 * 4 + r;
                *(ushort*)(smem + j * 256 + ((col * 2) ^ ((j & 15) << 4))) =
                    f2b(racc[n][r] + pb);
            }
        }
    }
    __syncthreads();   // REL complete (X-build reads rows written by other waves)

    // ---- phase 1: X = q_i - k_j + rel -> XS @16K (bf16 swz); rows 50..63 zero ----
    #pragma unroll
    for (int cc = 0; cc < 4; ++cc) {
        int c = cc * 256 + t;
        int row = c >> 4, g = c & 15;
        bf16x8 tv;
        if (row < 50) {
            long kq = (long)biL * 384;
            long kk = (long)(bL * 50 + row) * 384 + 128;
            bf16x8 rv = *(const bf16x8*)(smem + row * 256 + ((g * 16) ^ ((row & 15) << 4)));
            #pragma unroll
            for (int e = 0; e < 8; ++e) {
                int col = g * 8 + e;
                float v = qkv[kq + col] - qkv[kk + col] + b2f((ushort)rv[e]);
                tv[e] = (short)f2b(v);
            }
        } else {
            #pragma unroll
            for (int e = 0; e < 8; ++e) tv[e] = 0;
        }
        *(bf16x8*)(smem + 16384 + row * 256 + ((g * 16) ^ ((row & 15) << 4))) = tv;
    }
    __syncthreads();   // XS complete

    // ---- main loop: 4 e8-pairs, ZERO barriers ----
    f32x4 acc2[4][8];
    #pragma unroll
    for (int jt = 0; jt < 4; ++jt)
        #pragma unroll
        for (int n2 = 0; n2 < 8; ++n2) acc2[jt][n2] = f32x4{0.f, 0.f, 0.f, 0.f};

    #pragma unroll 1
    for (int p = 0; p < 4; ++p) {
        // GEMM1-swapped: H^T rows = wave's 16 hcols of e8a/e8b, cols = all 64 j
        f32x4 acc1a[4], acc1b[4];
        #pragma unroll
        for (int jt = 0; jt < 4; ++jt) {
            acc1a[jt] = f32x4{0.f, 0.f, 0.f, 0.f};
            acc1b[jt] = f32x4{0.f, 0.f, 0.f, 0.f};
        }
        #pragma unroll
        for (int kt = 0; kt < 4; ++kt) {
            int k0 = kt * 32 + hi4 * 8;
            bf16x8 w1a = *(const bf16x8*)&W1b[((p * 2) * 64 + w * 16 + lo16) * 128 + k0];
            bf16x8 w1c = *(const bf16x8*)&W1b[((p * 2 + 1) * 64 + w * 16 + lo16) * 128 + k0];
            #pragma unroll
            for (int jt = 0; jt < 4; ++jt) {
                int row = jt * 16 + lo16;
                bf16x8 xf = *(const bf16x8*)(smem + 16384 + row * 256 +
                              ((k0 * 2) ^ ((row & 15) << 4)));
                acc1a[jt] = __builtin_amdgcn_mfma_f32_16x16x32_bf16(w1a, xf, acc1a[jt], 0, 0, 0);
                acc1b[jt] = __builtin_amdgcn_mfma_f32_16x16x32_bf16(w1c, xf, acc1b[jt], 0, 0, 0);
            }
        }
        // bias + relu + pack into GEMM2 A-frags, k-order (hi4, e8sel, r)
        int hb = w * 16 + hi4 * 4;
        float ba[4], bb[4];
        #pragma unroll
        for (int r = 0; r < 4; ++r) {
            ba[r] = b1[(p * 2) * 64 + hb + r];
            bb[r] = b1[(p * 2 + 1) * 64 + hb + r];
        }
        bf16x8 a2[4];
        #pragma unroll
        for (int jt = 0; jt < 4; ++jt)
            #pragma unroll
            for (int r = 0; r < 4; ++r) {
                a2[jt][r]     = (short)f2b(fmaxf(acc1a[jt][r] + ba[r], 0.f));
                a2[jt][4 + r] = (short)f2b(fmaxf(acc1b[jt][r] + bb[r], 0.f));
            }
        // GEMM2 K-partial: all 128 d2 over the wave's 32 hcols
        #pragma unroll
        for (int n2 = 0; n2 < 8; ++n2) {
            bf16x8 w2f = *(const bf16x8*)&W2p[w * 16384 + p * 4096 + n2 * 512 +
                                              hi4 * 128 + lo16 * 8];
            #pragma unroll
            for (int jt = 0; jt < 4; ++jt)
                acc2[jt][n2] = __builtin_amdgcn_mfma_f32_16x16x32_bf16(a2[jt], w2f, acc2[jt][n2], 0, 0, 0);
        }
    }

    // ---- own-slice extraction (all indices literal) ----
    f32x4 own[4][2];
    #pragma unroll
    for (int n2 = 0; n2 < 8; ++n2)
        if ((n2 >> 1) == w) {
            #pragma unroll
            for (int jt = 0; jt < 4; ++jt) own[jt][n2 & 1] = acc2[jt][n2];
        }

    // ---- cross-wave reduce: round rho collects slice rho for wave rho ----
    #pragma unroll
    for (int rho = 0; rho < 4; ++rho) {
        if (w != rho) {
            float* bw = (float*)(smem + 32768 + w * 8192);
            #pragma unroll
            for (int jt = 0; jt < 4; ++jt)
                #pragma unroll
                for (int n = 0; n < 2; ++n)
                    #pragma unroll
                    for (int r = 0; r < 4; ++r)
                        bw[((jt * 2 + n) * 4 + r) * 64 + lane] = acc2[jt][rho * 2 + n][r];
        }
        __syncthreads();
        if (w == rho) {
            #pragma unroll
            for (int vw = 0; vw < 4; ++vw)
                if (vw != rho) {
                    const float* br = (const float*)(smem + 32768 + vw * 8192);
                    #pragma unroll
                    for (int jt = 0; jt < 4; ++jt)
                        #pragma unroll
                        for (int n = 0; n < 2; ++n)
                            #pragma unroll
                            for (int r = 0; r < 4; ++r)
                                own[jt][n][r] += br[((jt * 2 + n) * 4 + r) * 64 + lane];
                }
        }
        __syncthreads();
    }

    // ---- softmax over j + agg (v_ij = v + rel, rel from REL @0) ----
    float outv[2];
    #pragma unroll
    for (int n = 0; n < 2; ++n) {
        float mx = -1e30f;
        #pragma unroll
        for (int m = 0; m < 4; ++m)
            #pragma unroll
            for (int r = 0; r < 4; ++r) {
                int j = m * 16 + hi4 * 4 + r;
                if (j < 50) mx = fmaxf(mx, own[m][n][r]);
            }
        mx = fmaxf(mx, __shfl_xor(mx, 16, 64));
        mx = fmaxf(mx, __shfl_xor(mx, 32, 64));
        float e[4][4];
        float sum = 0.f;
        #pragma unroll
        for (int m = 0; m < 4; ++m)
            #pragma unroll
            for (int r = 0; r < 4; ++r) {
                int j = m * 16 + hi4 * 4 + r;
                float ev = (j < 50) ? __expf(own[m][n][r] - mx) : 0.f;
                e[m][r] = ev; sum += ev;
            }
        sum += __shfl_xor(sum, 16, 64);
        sum += __shfl_xor(sum, 32, 64);
        float inv = 1.f / sum;
        int col = w * 32 + n * 16 + lo16;
        float ag = 0.f;
        #pragma unroll
        for (int m = 0; m < 4; ++m)
            #pragma unroll
            for (int r = 0; r < 4; ++r) {
                int j = m * 16 + hi4 * 4 + r;
                if (j < 50) {
                    float rl = b2f(*(const ushort*)(smem + j * 256 +
                                  ((col * 2) ^ ((j & 15) << 4))));
                    float vv = qkv[(long)(bL * 50 + j) * 384 + 256 + col] + rl;
                    ag += e[m][r] * inv * vv;
                }
            }
        ag += __shfl_xor(ag, 16, 64);
        ag += __shfl_xor(ag, 32, 64);
        outv[n] = ag;
    }
    float* aggF = (float*)(smem + 32768);
    if (hi4 == 0) {
        aggF[w * 32 + lo16] = outv[0];
        aggF[w * 32 + 16 + lo16] = outv[1];
    }
    __syncthreads();

    // fused fl3 + tanh
    if (t < 36) {
        float s = fl3b[t];
        const float* wf = &fl3W[t * 128];
        #pragma unroll 8
        for (int d = 0; d < 128; ++d) s += aggF[d] * wf[d];
        out[(mbase + biL) * 36 + t] = tanhf(s);
    }
}

// ---------------- launch ----------------
struct Bufs {
    float *sk, *aux, *qkvF, *posb, *WcF, *bc;
    ushort *xh, *xl, *actAh, *actAl, *actBh, *actBl;
    ushort *l0Wh, *l0Wl, *resWh, *resWl, *Wch, *Wcl, *aW1b, *aW2b, *pW2b;
};

static size_t plan_ws(char* ws, long MCr, Bufs& B) {
    size_t off = 0;
    auto alloc = [&](size_t n) { char* p = ws + off; off += (n + 255) & ~(size_t)255; return p; };
    B.sk    = (float*) alloc(12800L * 4);
    B.aux   = (float*) alloc(128000L * 4);
    B.xh    = (ushort*)alloc((size_t)MCr * 288 * 2);
    B.xl    = (ushort*)alloc((size_t)MCr * 288 * 2);
    B.actAh = (ushort*)alloc((size_t)MCr * 1024 * 2);
    B.actAl = (ushort*)alloc((size_t)MCr * 1024 * 2);
    B.actBh = (ushort*)alloc((size_t)MCr * 1024 * 2);
    B.actBl = (ushort*)alloc((size_t)MCr * 1024 * 2);
    B.qkvF  = (float*) alloc((size_t)MCr * 384 * 4);
    B.posb  = (float*) alloc((size_t)MCr * 3 * 4);
    B.l0Wh  = (ushort*)alloc(1024L * 288 * 2);
    B.l0Wl  = (ushort*)alloc(1024L * 288 * 2);
    B.resWh = (ushort*)alloc(6144L * 1024 * 2);
    B.resWl = (ushort*)alloc(6144L * 1024 * 2);
    B.WcF   = (float*) alloc(384L * 1024 * 4);
    B.Wch   = (ushort*)alloc(384L * 1024 * 2);
    B.Wcl   = (ushort*)alloc(384L * 1024 * 2);
    B.bc    = (float*) alloc(384L * 4);
    B.aW1b  = (ushort*)alloc(512L * 128 * 2);
    B.aW2b  = (ushort*)alloc(128L * 512 * 2);   // holds W2p (prepacked), 65536 ushorts
    B.pW2b  = (ushort*)alloc(128L * 64 * 2);
    return off;
}

extern "C" void kernel_launch(void* const* d_in, const int* in_sizes, int n_in,
                              void* d_out, int out_size, void* d_ws, size_t ws_size,
                              hipStream_t stream) {
    (void)in_sizes; (void)n_in;
    const float* input  = (const float*)d_in[0];
    const float* fskel  = (const float*)d_in[1];
    const float* noise  = (const float*)d_in[2];
    const float* firstW = (const float*)d_in[3];
    const float* firstB = (const float*)d_in[4];
    const float* gWih   = (const float*)d_in[5];
    const float* gWhh   = (const float*)d_in[6];
    const float* gbih   = (const float*)d_in[7];
    const float* gbhh   = (const float*)d_in[8];
    const float* l0W    = (const float*)d_in[9];
    const float* l0b    = (const float*)d_in[10];
    const float* resW   = (const float*)d_in[11];
    const float* resB   = (const float*)d_in[12];
    const float* bnG    = (const float*)d_in[13];
    const float* bnB    = (const float*)d_in[14];
    const float* bnM    = (const float*)d_in[15];
    const float* bnV    = (const float*)d_in[16];
    const float* fl1W   = (const float*)d_in[17];
    const float* fl1b   = (const float*)d_in[18];
    const float* fl2W   = (const float*)d_in[19];
    const float* fl2b   = (const float*)d_in[20];
    const float* fl3W   = (const float*)d_in[21];
    const float* fl3b   = (const float*)d_in[22];
    const float* qkvW   = (const float*)d_in[23];
    const float* pW1    = (const float*)d_in[24];
    const float* pb1    = (const float*)d_in[25];
    const float* pW2    = (const float*)d_in[26];
    const float* pb2    = (const float*)d_in[27];
    const float* aW1    = (const float*)d_in[28];
    const float* ab1    = (const float*)d_in[29];
    const float* aW2    = (const float*)d_in[30];
    float* out = (float*)d_out;

    char* ws = (char*)d_ws;
    Bufs B;
    long MCr = 12800;                         // single chunk if it fits
    if (plan_ws(ws, MCr, B) > ws_size) {
        MCr = 6400;
        if (plan_ws(ws, MCr, B) > ws_size) {  // diagnostic: clean zero output
            hipMemsetAsync(d_out, 0, (size_t)out_size * sizeof(float), stream);
            return;
        }
    }
    const int nchunks = (int)(12800 / MCr);

    // one-time prep
    k_split<<<1152, 256, 0, stream>>>(l0W, B.l0Wh, B.l0Wl, 1024, 267, 288);
    k_split<<<8192, 256, 0, stream>>>(resW, B.resWh, B.resWl, 6144, 1024, 1024);
    k_wc<<<1536, 256, 0, stream>>>(qkvW, fl1W, fl1b, B.WcF, B.bc);
    k_split<<<1536, 256, 0, stream>>>(B.WcF, B.Wch, B.Wcl, 384, 1024, 1024);
    k_split<<<256, 256, 0, stream>>>(aW1, B.aW1b, nullptr, 512, 128, 128);
    k_w2p<<<256, 256, 0, stream>>>(aW2, B.aW2b);
    k_split<<<32, 256, 0, stream>>>(pW2, B.pW2b, nullptr, 128, 64, 64);
    k_sk<<<50, 256, 0, stream>>>(fskel, firstW, firstB, B.sk);
    k_gru<<<256, 64, 0, stream>>>(noise, gWih, gWhh, gbih, gbhh, B.aux);

    for (int c = 0; c < nchunks; ++c) {
        long mbase = (long)c * MCr;
        int xb_grid = (int)((MCr * 288 + 255) / 256);
        k_xbuild<<<xb_grid, 256, 0, stream>>>(input + mbase * 256, B.aux + mbase * 10,
                                              B.sk + mbase, B.xh, B.xl, MCr);
        dim3 gt(8, (unsigned)(MCr / 128));
        k_gemm<0><<<gt, 256, 0, stream>>>(B.xh, B.xl, B.l0Wh, B.l0Wl, 1024, 288,
            nullptr, B.actAh, B.actAl, l0b, nullptr, nullptr, nullptr, nullptr,
            nullptr, nullptr);
        for (int blk = 0; blk < 3; ++blk) {
            int j0 = blk * 2, j1 = blk * 2 + 1;
            k_gemm<1><<<gt, 256, 0, stream>>>(B.actAh, B.actAl,
                B.resWh + (size_t)j0 * 1024 * 1024, B.resWl + (size_t)j0 * 1024 * 1024,
                1024, 1024, nullptr, B.actBh, B.actBl, resB + j0 * 1024,
                bnG + j0 * 1024, bnB + j0 * 1024, bnM + j0 * 1024, bnV + j0 * 1024,
                nullptr, nullptr);
            k_gemm<2><<<gt, 256, 0, stream>>>(B.actBh, B.actBl,
                B.resWh + (size_t)j1 * 1024 * 1024, B.resWl + (size_t)j1 * 1024 * 1024,
                1024, 1024, nullptr, B.actAh, B.actAl, resB + j1 * 1024,
                bnG + j1 * 1024, bnB + j1 * 1024, bnM + j1 * 1024, bnV + j1 * 1024,
                B.actAh, B.actAl);
        }
        dim3 gq(3, (unsigned)(MCr / 128));
        k_gemm<0><<<gq, 256, 0, stream>>>(B.actAh, B.actAl, B.Wch, B.Wcl, 384, 1024,
            B.qkvF, nullptr, nullptr, B.bc, nullptr, nullptr, nullptr, nullptr,
            nullptr, nullptr);
        k_fl2<<<(int)(MCr / 4), 256, 0, stream>>>(B.actAh, B.actAl, fl2W, fl2b, B.posb);
        k_attn<<<(int)MCr, 256, 0, stream>>>(B.qkvF, B.posb, B.aW1b, B.aW2b, ab1, B.pW2b,
                                             pW1, pb1, pb2, fl3W, fl3b, out, mbase);
    }
}

// Round 6
// 1570.768 us; speedup vs baseline: 1.0393x; 1.0393x over previous
//
#include <hip/hip_runtime.h>

typedef __attribute__((ext_vector_type(8))) short bf16x8;
typedef __attribute__((ext_vector_type(4))) float f32x4;
typedef __attribute__((ext_vector_type(4))) ushort u16x4;

// HW bf16 convert (RNE), gfx950 v_cvt_pk_bf16_f32: 2 floats -> 1 VGPR (1 op)
__device__ __forceinline__ unsigned f2b2(float lo, float hi) {
    unsigned r;
    asm("v_cvt_pk_bf16_f32 %0, %1, %2" : "=v"(r) : "v"(lo), "v"(hi));
    return r;
}
__device__ __forceinline__ ushort f2b(float v) {
    return (ushort)f2b2(v, v);
}
__device__ __forceinline__ float b2f(ushort b) {
    union { float f; unsigned u; } x; x.u = ((unsigned)b) << 16; return x.f;
}

// async global->LDS 16B per lane; LDS dest = wave-uniform base + lane*16
__device__ __forceinline__ void gl_lds16(const void* g, void* l) {
    __builtin_amdgcn_global_load_lds(
        (__attribute__((address_space(1))) void*)(g),
        (__attribute__((address_space(3))) void*)(l), 16, 0, 0);
}

// ---------------- prep kernels ----------------

__global__ void k_split(const float* __restrict__ src, ushort* __restrict__ hi,
                        ushort* __restrict__ lo, int rows, int K, int Kpad) {
    long total = (long)rows * Kpad;
    for (long idx = (long)blockIdx.x * 256 + threadIdx.x; idx < total;
         idx += (long)gridDim.x * 256) {
        int r = (int)(idx / Kpad), c = (int)(idx % Kpad);
        float v = (c < K) ? src[(long)r * K + c] : 0.f;
        ushort h = f2b(v);
        hi[idx] = h;
        if (lo) lo[idx] = f2b(v - b2f(h));
    }
}

// Wc[n][k] = sum_d qkvW[n][d] * fl1W[d][k];  bc[n] = sum_d qkvW[n][d] * fl1b[d]
__global__ void k_wc(const float* __restrict__ qkvW, const float* __restrict__ fl1W,
                     const float* __restrict__ fl1b, float* __restrict__ Wc,
                     float* __restrict__ bc) {
    int idx = blockIdx.x * 256 + threadIdx.x;
    if (idx >= 384 * 1024) return;
    int n = idx >> 10, k = idx & 1023;
    float s = 0.f;
    #pragma unroll 8
    for (int d = 0; d < 128; ++d) s += qkvW[n * 128 + d] * fl1W[d * 1024 + k];
    Wc[idx] = s;
    if (k == 0) {
        float sb = 0.f;
        #pragma unroll 8
        for (int d = 0; d < 128; ++d) sb += qkvW[n * 128 + d] * fl1b[d];
        bc[n] = sb;
    }
}

__global__ void k_sk(const float* __restrict__ fs, const float* __restrict__ fW,
                     const float* __restrict__ fb, float* __restrict__ sk) {
    int m = blockIdx.x * 256 + threadIdx.x;
    if (m >= 12800) return;
    int b = m / 50, i = m % 50;
    float s = fb[i];
    #pragma unroll 4
    for (int c = 0; c < 36; ++c) s += fs[b * 36 + c] * fW[i * 36 + c];
    sk[m] = s;
}

// GRU(10->10): one wave (=one block of 64) per batch element -> 256 CUs covered
__global__ void k_gru(const float* __restrict__ noise, const float* __restrict__ Wih,
                      const float* __restrict__ Whh, const float* __restrict__ bih,
                      const float* __restrict__ bhh, float* __restrict__ aux) {
    int lane = threadIdx.x & 63;
    int b = blockIdx.x;
    if (b >= 256) return;
    float wih[10] = {}, whh[10] = {};
    float bi = 0.f, bh = 0.f;
    if (lane < 30) {
        #pragma unroll
        for (int c = 0; c < 10; ++c) { wih[c] = Wih[lane * 10 + c]; whh[c] = Whh[lane * 10 + c]; }
        bi = bih[lane]; bh = bhh[lane];
    }
    float h = 0.f;
    for (int t = 0; t < 50; ++t) {
        float xr = (lane < 10) ? noise[(b * 50 + t) * 10 + lane] : 0.f;
        float gi = bi, gh = bh;
        #pragma unroll
        for (int c = 0; c < 10; ++c) {
            float xc = __shfl(xr, c, 64);
            float hc = __shfl(h, c, 64);
            gi += wih[c] * xc; gh += whh[c] * hc;
        }
        float siz = __shfl(gi, lane + 10, 64), shz = __shfl(gh, lane + 10, 64);
        float sin_ = __shfl(gi, lane + 20, 64), shn = __shfl(gh, lane + 20, 64);
        float r = 1.f / (1.f + expf(-(gi + gh)));
        float z = 1.f / (1.f + expf(-(siz + shz)));
        float n = tanhf(sin_ + r * shn);
        float hn = (1.f - z) * n + z * h;
        if (lane < 10) { h = hn; aux[(b * 50 + t) * 10 + lane] = tanhf(hn); }
    }
}

__global__ void k_xbuild(const float* __restrict__ input, const float* __restrict__ aux,
                         const float* __restrict__ sk, ushort* __restrict__ xhi,
                         ushort* __restrict__ xlo, long M) {
    long idx = (long)blockIdx.x * 256 + threadIdx.x;
    if (idx >= M * 288) return;
    int m = (int)(idx / 288), c = (int)(idx % 288);
    float v;
    if (c < 256) v = input[(long)m * 256 + c];
    else if (c < 266) v = aux[m * 10 + (c - 256)];
    else if (c == 266) v = sk[m];
    else v = 0.f;
    ushort h = f2b(v);
    xhi[idx] = h;
    xlo[idx] = f2b(v - b2f(h));
}

// ---------------- split-bf16 MFMA GEMM, global_load_lds staging ----------------
// XCD-aware bijective remap (m204): each XCD gets a contiguous wgid range,
// ordered x-fast/y-slow so its B working set stays L2-resident and each
// A-tile is reused by consecutive same-XCD blocks.
template <int MODE>
__global__ __launch_bounds__(256, 3) void k_gemm(
    const ushort* __restrict__ Ahi, const ushort* __restrict__ Alo,
    const ushort* __restrict__ Bhi, const ushort* __restrict__ Blo,
    int N, int K,
    float* outF, ushort* outHi, ushort* outLo,
    const float* __restrict__ bias,
    const float* __restrict__ bng, const float* __restrict__ bnb,
    const float* __restrict__ bnm, const float* __restrict__ bnv,
    const ushort* resHi, const ushort* resLo) {
    __shared__ __align__(16) ushort S[4][128][32];   // Ah, Al, Bh, Bl : 32 KB
    int t = threadIdx.x;
    // XCD swizzle
    int flat = blockIdx.y * gridDim.x + blockIdx.x;
    int nwg = gridDim.x * gridDim.y;
    int q = nwg >> 3, r = nwg & 7;
    int xcd = flat & 7, seq = flat >> 3;
    int wgid = (xcd < r ? xcd * (q + 1) : r * (q + 1) + (xcd - r) * q) + seq;
    int bx = wgid % gridDim.x, by = wgid / gridDim.x;
    int m0 = by * 128, n0 = bx * 128;
    int w = t >> 6, lane = t & 63;
    int wm = w >> 1, wn = w & 1;
    int lo16 = lane & 15, hi4 = lane >> 4;

    const int srow = lane >> 2;
    const int skoff = ((lane & 3) ^ (srow & 3)) * 8;   // elements
    const int slot8 = (hi4 ^ (lo16 & 3)) * 8;

    f32x4 acc[4][4];
    #pragma unroll
    for (int i = 0; i < 4; ++i)
        #pragma unroll
        for (int j = 0; j < 4; ++j) acc[i][j] = f32x4{0.f, 0.f, 0.f, 0.f};

    const int nk = K / 32;
    for (int kt = 0; kt < nk; ++kt) {
        const int kb = kt * 32;
        #pragma unroll
        for (int i = 0; i < 2; ++i) {
            int rg = w * 32 + i * 16;              // wave-uniform row-group base
            long ga = (long)(m0 + rg + srow) * K + kb + skoff;
            long gb = (long)(n0 + rg + srow) * K + kb + skoff;
            gl_lds16(&Ahi[ga], &S[0][rg][0]);
            gl_lds16(&Alo[ga], &S[1][rg][0]);
            gl_lds16(&Bhi[gb], &S[2][rg][0]);
            gl_lds16(&Blo[gb], &S[3][rg][0]);
        }
        __syncthreads();
        bf16x8 ah[4], al[4], bh[4], bl[4];
        #pragma unroll
        for (int m = 0; m < 4; ++m) {
            int row = wm * 64 + m * 16 + lo16;
            ah[m] = *(const bf16x8*)&S[0][row][slot8];
            al[m] = *(const bf16x8*)&S[1][row][slot8];
        }
        #pragma unroll
        for (int n = 0; n < 4; ++n) {
            int col = wn * 64 + n * 16 + lo16;
            bh[n] = *(const bf16x8*)&S[2][col][slot8];
            bl[n] = *(const bf16x8*)&S[3][col][slot8];
        }
        #pragma unroll
        for (int m = 0; m < 4; ++m)
            #pragma unroll
            for (int n = 0; n < 4; ++n) {
                acc[m][n] = __builtin_amdgcn_mfma_f32_16x16x32_bf16(ah[m], bh[n], acc[m][n], 0, 0, 0);
                acc[m][n] = __builtin_amdgcn_mfma_f32_16x16x32_bf16(ah[m], bl[n], acc[m][n], 0, 0, 0);
                acc[m][n] = __builtin_amdgcn_mfma_f32_16x16x32_bf16(al[m], bh[n], acc[m][n], 0, 0, 0);
            }
        __syncthreads();
    }

    #pragma unroll
    for (int n = 0; n < 4; ++n) {
        int gn = n0 + wn * 64 + n * 16 + lo16;
        float bv = bias ? bias[gn] : 0.f;
        float sc = 1.f, sh = 0.f;
        if (MODE >= 1) { sc = bng[gn] * rsqrtf(bnv[gn] + 1e-5f); sh = bnb[gn] - bnm[gn] * sc; }
        #pragma unroll
        for (int m = 0; m < 4; ++m)
            #pragma unroll
            for (int r2 = 0; r2 < 4; ++r2) {
                int gm = m0 + wm * 64 + m * 16 + hi4 * 4 + r2;
                long o = (long)gm * N + gn;
                float v = acc[m][n][r2] + bv;
                if (MODE >= 1) v = fmaxf(v * sc + sh, 0.f);
                if (MODE == 2) v += b2f(resHi[o]) + b2f(resLo[o]);
                if (outF) outF[o] = v;
                if (outHi) {
                    ushort hb = f2b(v);
                    outHi[o] = hb;
                    outLo[o] = f2b(v - b2f(hb));
                }
            }
    }
}

// ---------------- pos (fl2): wave-per-row, vectorized hi/lo loads ----------------
__global__ void k_fl2(const ushort* __restrict__ hA, const ushort* __restrict__ lA,
                      const float* __restrict__ W, const float* __restrict__ bias,
                      float* __restrict__ pos) {
    int w = threadIdx.x >> 6, lane = threadIdx.x & 63;
    int m = blockIdx.x * 4 + w;
    float a0 = 0.f, a1 = 0.f, a2 = 0.f;
    for (int k0 = lane * 4; k0 < 1024; k0 += 256) {
        long o = (long)m * 1024 + k0;
        u16x4 hv = *(const u16x4*)&hA[o];
        u16x4 lv = *(const u16x4*)&lA[o];
        f32x4 w0 = *(const f32x4*)&W[k0];
        f32x4 w1 = *(const f32x4*)&W[1024 + k0];
        f32x4 w2 = *(const f32x4*)&W[2048 + k0];
        #pragma unroll
        for (int e = 0; e < 4; ++e) {
            float x = b2f(hv[e]) + b2f(lv[e]);
            a0 += x * w0[e]; a1 += x * w1[e]; a2 += x * w2[e];
        }
    }
    #pragma unroll
    for (int off = 32; off; off >>= 1) {
        a0 += __shfl_xor(a0, off, 64);
        a1 += __shfl_xor(a1, off, 64);
        a2 += __shfl_xor(a2, off, 64);
    }
    if (lane == 0) {
        pos[m * 3 + 0] = a0 + bias[0];
        pos[m * 3 + 1] = a1 + bias[1];
        pos[m * 3 + 2] = a2 + bias[2];
    }
}

// ---------------- fused attention (+rel_emb +fl3) per (b,i) block ----------------
// R11: the 600us R0 structure (col-split GEMM1 with 4x B-reuse, single HE
// buffer, 2 barriers/e8, 40KB LDS, (256,3)) + three VALU-budget cuts:
//  (a) all bf16 converts via HW v_cvt_pk_bf16_f32 (1 op / 2 values, RNE ==
//      old bit-twiddle) -- was ~5-6 VALU ops per value, ~1100 values/wave.
//  (b) register h1/rel prologue (verified R6-R10, cheaper than LDS roundtrip).
//  (c) fl3 tail 4-wave-parallel over d-quarters (wave-local aggF slices, DS
//      in-order -> no extra barrier); was a 128-deep serial chain on 36 lanes.
//  X-build qkv loads vectorized f32x4 (16 scalar -> 4 vector loads).
// LDS map (40KB -> 3 blocks/CU, reg-capped):
//   [0,16384)      REL[64][256B pitch], swz byte = j*256 + ((d*2)^((j&15)<<4))
//   [16384,32768)  XS[64][256B pitch], same swz
//   [32768,40960)  HE[64 rows][128B pitch], swz (c*2)^((r&7)<<4)
//   aggF f32[128] @16384, fl3 partials f32[4][36] @16896 (XS dead by then).
__global__ __launch_bounds__(256, 3) void k_attn(
    const float* __restrict__ qkv, const float* __restrict__ posb,
    const ushort* __restrict__ W1b, const ushort* __restrict__ W2b,
    const float* __restrict__ b1, const ushort* __restrict__ pW2b,
    const float* __restrict__ pW1, const float* __restrict__ pb1,
    const float* __restrict__ pb2,
    const float* __restrict__ fl3W, const float* __restrict__ fl3b,
    float* __restrict__ out, long mbase) {
    __shared__ __align__(16) char smem[40960];
    // XCD-aware swizzle: gridDim.x % 8 == 0 always (12800 or 6400)
    int cpx = gridDim.x >> 3;
    int biL = (blockIdx.x & 7) * cpx + (blockIdx.x >> 3);
    int bL = biL / 50;
    int t = threadIdx.x, w = t >> 6, lane = t & 63;
    int lo16 = lane & 15, hi4 = lane >> 4;

    // ---- phase 0a: h1 fragments in registers (row-split, wave-private) ----
    // lane holds h1[jrow][k] for jrow = w*16+lo16, k = kt*32 + hi4*8 + e
    bf16x8 h_a[2];
    {
        const int jrow = w * 16 + lo16;
        const bool jvalid = jrow < 50;
        float pi0 = posb[biL * 3], pi1 = posb[biL * 3 + 1], pi2 = posb[biL * 3 + 2];
        float d0 = 0.f, d1 = 0.f, d2 = 0.f;
        if (jvalid) {
            int pj = (bL * 50 + jrow) * 3;
            d0 = pi0 - posb[pj]; d1 = pi1 - posb[pj + 1]; d2 = pi2 - posb[pj + 2];
        }
        #pragma unroll
        for (int kt = 0; kt < 2; ++kt) {
            float hv[8];
            #pragma unroll
            for (int e = 0; e < 8; ++e) {
                int ke = kt * 32 + hi4 * 8 + e;
                hv[e] = jvalid
                    ? fmaxf(pb1[ke] + pW1[ke * 3] * d0 + pW1[ke * 3 + 1] * d1
                            + pW1[ke * 3 + 2] * d2, 0.f)
                    : 0.f;
            }
            unsigned* hu = (unsigned*)&h_a[kt];
            #pragma unroll
            for (int i = 0; i < 4; ++i) hu[i] = f2b2(hv[2 * i], hv[2 * i + 1]);
        }
    }

    // ---- phase 0b: rel rows for own 16 j (MFMA K=64) -> REL (wave-private) ----
    {
        f32x4 racc[8];
        #pragma unroll
        for (int n = 0; n < 8; ++n) racc[n] = f32x4{0.f, 0.f, 0.f, 0.f};
        #pragma unroll
        for (int kt = 0; kt < 2; ++kt) {
            int k0 = kt * 32 + hi4 * 8;
            #pragma unroll
            for (int n = 0; n < 8; ++n) {
                bf16x8 bv = *(const bf16x8*)&pW2b[(n * 16 + lo16) * 64 + k0];
                racc[n] = __builtin_amdgcn_mfma_f32_16x16x32_bf16(h_a[kt], bv, racc[n], 0, 0, 0);
            }
        }
        int j0 = w * 16 + hi4 * 4;
        #pragma unroll
        for (int n = 0; n < 8; ++n) {
            int col = n * 16 + lo16;
            float pb = pb2[col];
            unsigned p01 = f2b2(racc[n][0] + pb, racc[n][1] + pb);
            unsigned p23 = f2b2(racc[n][2] + pb, racc[n][3] + pb);
            *(ushort*)(smem + (j0 + 0) * 256 + ((col * 2) ^ (((j0 + 0) & 15) << 4))) = (ushort)p01;
            *(ushort*)(smem + (j0 + 1) * 256 + ((col * 2) ^ (((j0 + 1) & 15) << 4))) = (ushort)(p01 >> 16);
            *(ushort*)(smem + (j0 + 2) * 256 + ((col * 2) ^ (((j0 + 2) & 15) << 4))) = (ushort)p23;
            *(ushort*)(smem + (j0 + 3) * 256 + ((col * 2) ^ (((j0 + 3) & 15) << 4))) = (ushort)(p23 >> 16);
        }
    }
    __syncthreads();   // REL complete (X-build reads rows written by other waves)

    // ---- phase 1: X = q_i - k_j + rel -> XS @16K (bf16 swz); rows 50..63 zero ----
    #pragma unroll
    for (int cc = 0; cc < 4; ++cc) {
        int c = cc * 256 + t;
        int row = c >> 4, g = c & 15;
        bf16x8 tv;
        if (row < 50) {
            long kq = (long)biL * 384 + g * 8;
            long kk = (long)(bL * 50 + row) * 384 + 128 + g * 8;
            f32x4 q0 = *(const f32x4*)&qkv[kq];
            f32x4 q1 = *(const f32x4*)&qkv[kq + 4];
            f32x4 k0 = *(const f32x4*)&qkv[kk];
            f32x4 k1 = *(const f32x4*)&qkv[kk + 4];
            bf16x8 rv = *(const bf16x8*)(smem + row * 256 + ((g * 16) ^ ((row & 15) << 4)));
            unsigned* tu = (unsigned*)&tv;
            #pragma unroll
            for (int i = 0; i < 2; ++i)
                tu[i] = f2b2(q0[2 * i] - k0[2 * i] + b2f((ushort)rv[2 * i]),
                             q0[2 * i + 1] - k0[2 * i + 1] + b2f((ushort)rv[2 * i + 1]));
            #pragma unroll
            for (int i = 0; i < 2; ++i)
                tu[2 + i] = f2b2(q1[2 * i] - k1[2 * i] + b2f((ushort)rv[4 + 2 * i]),
                                 q1[2 * i + 1] - k1[2 * i + 1] + b2f((ushort)rv[4 + 2 * i + 1]));
        } else {
            #pragma unroll
            for (int e = 0; e < 8; ++e) tv[e] = 0;
        }
        *(bf16x8*)(smem + 16384 + row * 256 + ((g * 16) ^ ((row & 15) << 4))) = tv;
    }
    __syncthreads();   // XS complete

    // ---- main loop: 8 eighths of H (64 cols each), 2 barriers per e8 ----
    f32x4 acc2[4][2];
    #pragma unroll
    for (int m = 0; m < 4; ++m)
        #pragma unroll
        for (int n = 0; n < 2; ++n) acc2[m][n] = f32x4{0.f, 0.f, 0.f, 0.f};

    for (int e8 = 0; e8 < 8; ++e8) {
        // GEMM1: H[:, wave's 16 cols of e8] over K=128 (bv reused 4x)
        f32x4 acc1[4];
        #pragma unroll
        for (int m = 0; m < 4; ++m) acc1[m] = f32x4{0.f, 0.f, 0.f, 0.f};
        __builtin_amdgcn_s_setprio(1);
        #pragma unroll
        for (int kt = 0; kt < 4; ++kt) {
            int col = e8 * 64 + w * 16 + lo16;
            int k = kt * 32 + hi4 * 8;
            bf16x8 bfv = *(const bf16x8*)&W1b[(long)col * 128 + k];
            #pragma unroll
            for (int m = 0; m < 4; ++m) {
                int row = m * 16 + lo16;
                bf16x8 af = *(const bf16x8*)(smem + 16384 + row * 256 +
                          ((k * 2) ^ ((row & 15) << 4)));
                acc1[m] = __builtin_amdgcn_mfma_f32_16x16x32_bf16(af, bfv, acc1[m], 0, 0, 0);
            }
        }
        __builtin_amdgcn_s_setprio(0);
        __syncthreads();   // prev eighth's GEMM2 reads of HE done
        {
            int ch = w * 16 + lo16;             // local col in [0,64)
            float bv = b1[e8 * 64 + ch];
            int row0 = hi4 * 4;
            #pragma unroll
            for (int m = 0; m < 4; ++m) {
                unsigned p01 = f2b2(fmaxf(acc1[m][0] + bv, 0.f), fmaxf(acc1[m][1] + bv, 0.f));
                unsigned p23 = f2b2(fmaxf(acc1[m][2] + bv, 0.f), fmaxf(acc1[m][3] + bv, 0.f));
                int r0 = m * 16 + row0;
                *(ushort*)(smem + 32768 + (r0 + 0) * 128 + ((ch * 2) ^ (((r0 + 0) & 7) << 4))) = (ushort)p01;
                *(ushort*)(smem + 32768 + (r0 + 1) * 128 + ((ch * 2) ^ (((r0 + 1) & 7) << 4))) = (ushort)(p01 >> 16);
                *(ushort*)(smem + 32768 + (r0 + 2) * 128 + ((ch * 2) ^ (((r0 + 2) & 7) << 4))) = (ushort)p23;
                *(ushort*)(smem + 32768 + (r0 + 3) * 128 + ((ch * 2) ^ (((r0 + 3) & 7) << 4))) = (ushort)(p23 >> 16);
            }
        }
        __syncthreads();
        // GEMM2 partial: K chunk [e8*64, e8*64+64), HE @32K
        for (int kt2 = 0; kt2 < 2; ++kt2) {
            bf16x8 af[4];
            #pragma unroll
            for (int m = 0; m < 4; ++m) {
                int row = m * 16 + lo16;
                af[m] = *(const bf16x8*)(smem + 32768 + row * 128 +
                          (((kt2 * 32 + hi4 * 8) * 2) ^ ((row & 7) << 4)));
            }
            __builtin_amdgcn_s_setprio(1);
            #pragma unroll
            for (int n = 0; n < 2; ++n) {
                int col = w * 32 + n * 16 + lo16;
                int gk = e8 * 64 + kt2 * 32 + hi4 * 8;
                bf16x8 bfv = *(const bf16x8*)&W2b[(long)col * 512 + gk];
                #pragma unroll
                for (int m = 0; m < 4; ++m)
                    acc2[m][n] = __builtin_amdgcn_mfma_f32_16x16x32_bf16(af[m], bfv, acc2[m][n], 0, 0, 0);
            }
            __builtin_amdgcn_s_setprio(0);
        }
    }

    // ---- softmax over j + agg (v_ij = v + rel, rel from REL @0) ----
    float outv[2];
    #pragma unroll
    for (int n = 0; n < 2; ++n) {
        float mx = -1e30f;
        #pragma unroll
        for (int m = 0; m < 4; ++m)
            #pragma unroll
            for (int r = 0; r < 4; ++r) {
                int j = m * 16 + hi4 * 4 + r;
                if (j < 50) mx = fmaxf(mx, acc2[m][n][r]);
            }
        mx = fmaxf(mx, __shfl_xor(mx, 16, 64));
        mx = fmaxf(mx, __shfl_xor(mx, 32, 64));
        float e[4][4];
        float sum = 0.f;
        #pragma unroll
        for (int m = 0; m < 4; ++m)
            #pragma unroll
            for (int r = 0; r < 4; ++r) {
                int j = m * 16 + hi4 * 4 + r;
                float ev = (j < 50) ? __expf(acc2[m][n][r] - mx) : 0.f;
                e[m][r] = ev; sum += ev;
            }
        sum += __shfl_xor(sum, 16, 64);
        sum += __shfl_xor(sum, 32, 64);
        float inv = 1.f / sum;
        int col = w * 32 + n * 16 + lo16;
        float ag = 0.f;
        #pragma unroll
        for (int m = 0; m < 4; ++m)
            #pragma unroll
            for (int r = 0; r < 4; ++r) {
                int j = m * 16 + hi4 * 4 + r;
                if (j < 50) {
                    float rl = b2f(*(const ushort*)(smem + j * 256 +
                                  ((col * 2) ^ ((j & 15) << 4))));
                    float vv = qkv[(long)(bL * 50 + j) * 384 + 256 + col] + rl;
                    ag += e[m][r] * inv * vv;
                }
            }
        ag += __shfl_xor(ag, 16, 64);
        ag += __shfl_xor(ag, 32, 64);
        outv[n] = ag;
    }
    // aggF: each wave writes its own 32-col slice (cols w*32..w*32+32)
    float* aggF = (float*)(smem + 16384);
    float* part = (float*)(smem + 16896);   // f32[4][36]
    if (hi4 == 0) {
        aggF[w * 32 + lo16] = outv[0];
        aggF[w * 32 + 16 + lo16] = outv[1];
    }
    // fl3 partials: wave-local read of OWN aggF slice (same-wave DS ordering,
    // no barrier needed); each wave covers d-quarter [w*32, w*32+32)
    if (lane < 36) {
        const float* wf = &fl3W[lane * 128 + w * 32];
        const float* af = aggF + w * 32;
        float s = 0.f;
        #pragma unroll 8
        for (int d = 0; d < 32; ++d) s += af[d] * wf[d];
        part[w * 36 + lane] = s;
    }
    __syncthreads();

    // fused fl3 + tanh
    if (t < 36) {
        float s = fl3b[t] + part[t] + part[36 + t] + part[72 + t] + part[108 + t];
        out[(mbase + biL) * 36 + t] = tanhf(s);
    }
}

// ---------------- launch ----------------
struct Bufs {
    float *sk, *aux, *qkvF, *posb, *WcF, *bc;
    ushort *xh, *xl, *actAh, *actAl, *actBh, *actBl;
    ushort *l0Wh, *l0Wl, *resWh, *resWl, *Wch, *Wcl, *aW1b, *aW2b, *pW2b;
};

static size_t plan_ws(char* ws, long MCr, Bufs& B) {
    size_t off = 0;
    auto alloc = [&](size_t n) { char* p = ws + off; off += (n + 255) & ~(size_t)255; return p; };
    B.sk    = (float*) alloc(12800L * 4);
    B.aux   = (float*) alloc(128000L * 4);
    B.xh    = (ushort*)alloc((size_t)MCr * 288 * 2);
    B.xl    = (ushort*)alloc((size_t)MCr * 288 * 2);
    B.actAh = (ushort*)alloc((size_t)MCr * 1024 * 2);
    B.actAl = (ushort*)alloc((size_t)MCr * 1024 * 2);
    B.actBh = (ushort*)alloc((size_t)MCr * 1024 * 2);
    B.actBl = (ushort*)alloc((size_t)MCr * 1024 * 2);
    B.qkvF  = (float*) alloc((size_t)MCr * 384 * 4);
    B.posb  = (float*) alloc((size_t)MCr * 3 * 4);
    B.l0Wh  = (ushort*)alloc(1024L * 288 * 2);
    B.l0Wl  = (ushort*)alloc(1024L * 288 * 2);
    B.resWh = (ushort*)alloc(6144L * 1024 * 2);
    B.resWl = (ushort*)alloc(6144L * 1024 * 2);
    B.WcF   = (float*) alloc(384L * 1024 * 4);
    B.Wch   = (ushort*)alloc(384L * 1024 * 2);
    B.Wcl   = (ushort*)alloc(384L * 1024 * 2);
    B.bc    = (float*) alloc(384L * 4);
    B.aW1b  = (ushort*)alloc(512L * 128 * 2);
    B.aW2b  = (ushort*)alloc(128L * 512 * 2);
    B.pW2b  = (ushort*)alloc(128L * 64 * 2);
    return off;
}

extern "C" void kernel_launch(void* const* d_in, const int* in_sizes, int n_in,
                              void* d_out, int out_size, void* d_ws, size_t ws_size,
                              hipStream_t stream) {
    (void)in_sizes; (void)n_in;
    const float* input  = (const float*)d_in[0];
    const float* fskel  = (const float*)d_in[1];
    const float* noise  = (const float*)d_in[2];
    const float* firstW = (const float*)d_in[3];
    const float* firstB = (const float*)d_in[4];
    const float* gWih   = (const float*)d_in[5];
    const float* gWhh   = (const float*)d_in[6];
    const float* gbih   = (const float*)d_in[7];
    const float* gbhh   = (const float*)d_in[8];
    const float* l0W    = (const float*)d_in[9];
    const float* l0b    = (const float*)d_in[10];
    const float* resW   = (const float*)d_in[11];
    const float* resB   = (const float*)d_in[12];
    const float* bnG    = (const float*)d_in[13];
    const float* bnB    = (const float*)d_in[14];
    const float* bnM    = (const float*)d_in[15];
    const float* bnV    = (const float*)d_in[16];
    const float* fl1W   = (const float*)d_in[17];
    const float* fl1b   = (const float*)d_in[18];
    const float* fl2W   = (const float*)d_in[19];
    const float* fl2b   = (const float*)d_in[20];
    const float* fl3W   = (const float*)d_in[21];
    const float* fl3b   = (const float*)d_in[22];
    const float* qkvW   = (const float*)d_in[23];
    const float* pW1    = (const float*)d_in[24];
    const float* pb1    = (const float*)d_in[25];
    const float* pW2    = (const float*)d_in[26];
    const float* pb2    = (const float*)d_in[27];
    const float* aW1    = (const float*)d_in[28];
    const float* ab1    = (const float*)d_in[29];
    const float* aW2    = (const float*)d_in[30];
    float* out = (float*)d_out;

    char* ws = (char*)d_ws;
    Bufs B;
    long MCr = 12800;                         // single chunk if it fits
    if (plan_ws(ws, MCr, B) > ws_size) {
        MCr = 6400;
        if (plan_ws(ws, MCr, B) > ws_size) {  // diagnostic: clean zero output
            hipMemsetAsync(d_out, 0, (size_t)out_size * sizeof(float), stream);
            return;
        }
    }
    const int nchunks = (int)(12800 / MCr);

    // one-time prep
    k_split<<<1152, 256, 0, stream>>>(l0W, B.l0Wh, B.l0Wl, 1024, 267, 288);
    k_split<<<8192, 256, 0, stream>>>(resW, B.resWh, B.resWl, 6144, 1024, 1024);
    k_wc<<<1536, 256, 0, stream>>>(qkvW, fl1W, fl1b, B.WcF, B.bc);
    k_split<<<1536, 256, 0, stream>>>(B.WcF, B.Wch, B.Wcl, 384, 1024, 1024);
    k_split<<<256, 256, 0, stream>>>(aW1, B.aW1b, nullptr, 512, 128, 128);
    k_split<<<256, 256, 0, stream>>>(aW2, B.aW2b, nullptr, 128, 512, 512);
    k_split<<<32, 256, 0, stream>>>(pW2, B.pW2b, nullptr, 128, 64, 64);
    k_sk<<<50, 256, 0, stream>>>(fskel, firstW, firstB, B.sk);
    k_gru<<<256, 64, 0, stream>>>(noise, gWih, gWhh, gbih, gbhh, B.aux);

    for (int c = 0; c < nchunks; ++c) {
        long mbase = (long)c * MCr;
        int xb_grid = (int)((MCr * 288 + 255) / 256);
        k_xbuild<<<xb_grid, 256, 0, stream>>>(input + mbase * 256, B.aux + mbase * 10,
                                              B.sk + mbase, B.xh, B.xl, MCr);
        dim3 gt(8, (unsigned)(MCr / 128));
        k_gemm<0><<<gt, 256, 0, stream>>>(B.xh, B.xl, B.l0Wh, B.l0Wl, 1024, 288,
            nullptr, B.actAh, B.actAl, l0b, nullptr, nullptr, nullptr, nullptr,
            nullptr, nullptr);
        for (int blk = 0; blk < 3; ++blk) {
            int j0 = blk * 2, j1 = blk * 2 + 1;
            k_gemm<1><<<gt, 256, 0, stream>>>(B.actAh, B.actAl,
                B.resWh + (size_t)j0 * 1024 * 1024, B.resWl + (size_t)j0 * 1024 * 1024,
                1024, 1024, nullptr, B.actBh, B.actBl, resB + j0 * 1024,
                bnG + j0 * 1024, bnB + j0 * 1024, bnM + j0 * 1024, bnV + j0 * 1024,
                nullptr, nullptr);
            k_gemm<2><<<gt, 256, 0, stream>>>(B.actBh, B.actBl,
                B.resWh + (size_t)j1 * 1024 * 1024, B.resWl + (size_t)j1 * 1024 * 1024,
                1024, 1024, nullptr, B.actAh, B.actAl, resB + j1 * 1024,
                bnG + j1 * 1024, bnB + j1 * 1024, bnM + j1 * 1024, bnV + j1 * 1024,
                B.actAh, B.actAl);
        }
        dim3 gq(3, (unsigned)(MCr / 128));
        k_gemm<0><<<gq, 256, 0, stream>>>(B.actAh, B.actAl, B.Wch, B.Wcl, 384, 1024,
            B.qkvF, nullptr, nullptr, B.bc, nullptr, nullptr, nullptr, nullptr,
            nullptr, nullptr);
        k_fl2<<<(int)(MCr / 4), 256, 0, stream>>>(B.actAh, B.actAl, fl2W, fl2b, B.posb);
        k_attn<<<(int)MCr, 256, 0, stream>>>(B.qkvF, B.posb, B.aW1b, B.aW2b, ab1, B.pW2b,
                                             pW1, pb1, pb2, fl3W, fl3b, out, mbase);
    }
}

// Round 7
// 1225.021 us; speedup vs baseline: 1.3326x; 1.2822x over previous
//
#include <hip/hip_runtime.h>

typedef __attribute__((ext_vector_type(8))) short bf16x8;
typedef __attribute__((ext_vector_type(4))) float f32x4;
typedef __attribute__((ext_vector_type(4))) ushort u16x4;

// HW bf16 convert (RNE), gfx950 v_cvt_pk_bf16_f32: 2 floats -> 1 VGPR (1 op)
__device__ __forceinline__ unsigned f2b2(float lo, float hi) {
    unsigned r;
    asm("v_cvt_pk_bf16_f32 %0, %1, %2" : "=v"(r) : "v"(lo), "v"(hi));
    return r;
}
__device__ __forceinline__ ushort f2b(float v) {
    return (ushort)f2b2(v, v);
}
__device__ __forceinline__ float b2f(ushort b) {
    union { float f; unsigned u; } x; x.u = ((unsigned)b) << 16; return x.f;
}

// async global->LDS 16B per lane; LDS dest = wave-uniform base + lane*16
__device__ __forceinline__ void gl_lds16(const void* g, void* l) {
    __builtin_amdgcn_global_load_lds(
        (__attribute__((address_space(1))) void*)(g),
        (__attribute__((address_space(3))) void*)(l), 16, 0, 0);
}

// ---------------- prep kernels ----------------

__global__ void k_split(const float* __restrict__ src, ushort* __restrict__ hi,
                        ushort* __restrict__ lo, int rows, int K, int Kpad) {
    long total = (long)rows * Kpad;
    for (long idx = (long)blockIdx.x * 256 + threadIdx.x; idx < total;
         idx += (long)gridDim.x * 256) {
        int r = (int)(idx / Kpad), c = (int)(idx % Kpad);
        float v = (c < K) ? src[(long)r * K + c] : 0.f;
        ushort h = f2b(v);
        hi[idx] = h;
        if (lo) lo[idx] = f2b(v - b2f(h));
    }
}

// Wc[n][k] = sum_d qkvW[n][d] * fl1W[d][k];  bc[n] = sum_d qkvW[n][d] * fl1b[d]
__global__ void k_wc(const float* __restrict__ qkvW, const float* __restrict__ fl1W,
                     const float* __restrict__ fl1b, float* __restrict__ Wc,
                     float* __restrict__ bc) {
    int idx = blockIdx.x * 256 + threadIdx.x;
    if (idx >= 384 * 1024) return;
    int n = idx >> 10, k = idx & 1023;
    float s = 0.f;
    #pragma unroll 8
    for (int d = 0; d < 128; ++d) s += qkvW[n * 128 + d] * fl1W[d * 1024 + k];
    Wc[idx] = s;
    if (k == 0) {
        float sb = 0.f;
        #pragma unroll 8
        for (int d = 0; d < 128; ++d) sb += qkvW[n * 128 + d] * fl1b[d];
        bc[n] = sb;
    }
}

__global__ void k_sk(const float* __restrict__ fs, const float* __restrict__ fW,
                     const float* __restrict__ fb, float* __restrict__ sk) {
    int m = blockIdx.x * 256 + threadIdx.x;
    if (m >= 12800) return;
    int b = m / 50, i = m % 50;
    float s = fb[i];
    #pragma unroll 4
    for (int c = 0; c < 36; ++c) s += fs[b * 36 + c] * fW[i * 36 + c];
    sk[m] = s;
}

// GRU(10->10): one wave (=one block of 64) per batch element -> 256 CUs covered
__global__ void k_gru(const float* __restrict__ noise, const float* __restrict__ Wih,
                      const float* __restrict__ Whh, const float* __restrict__ bih,
                      const float* __restrict__ bhh, float* __restrict__ aux) {
    int lane = threadIdx.x & 63;
    int b = blockIdx.x;
    if (b >= 256) return;
    float wih[10] = {}, whh[10] = {};
    float bi = 0.f, bh = 0.f;
    if (lane < 30) {
        #pragma unroll
        for (int c = 0; c < 10; ++c) { wih[c] = Wih[lane * 10 + c]; whh[c] = Whh[lane * 10 + c]; }
        bi = bih[lane]; bh = bhh[lane];
    }
    float h = 0.f;
    for (int t = 0; t < 50; ++t) {
        float xr = (lane < 10) ? noise[(b * 50 + t) * 10 + lane] : 0.f;
        float gi = bi, gh = bh;
        #pragma unroll
        for (int c = 0; c < 10; ++c) {
            float xc = __shfl(xr, c, 64);
            float hc = __shfl(h, c, 64);
            gi += wih[c] * xc; gh += whh[c] * hc;
        }
        float siz = __shfl(gi, lane + 10, 64), shz = __shfl(gh, lane + 10, 64);
        float sin_ = __shfl(gi, lane + 20, 64), shn = __shfl(gh, lane + 20, 64);
        float r = 1.f / (1.f + expf(-(gi + gh)));
        float z = 1.f / (1.f + expf(-(siz + shz)));
        float n = tanhf(sin_ + r * shn);
        float hn = (1.f - z) * n + z * h;
        if (lane < 10) { h = hn; aux[(b * 50 + t) * 10 + lane] = tanhf(hn); }
    }
}

__global__ void k_xbuild(const float* __restrict__ input, const float* __restrict__ aux,
                         const float* __restrict__ sk, ushort* __restrict__ xhi,
                         ushort* __restrict__ xlo, long M) {
    long idx = (long)blockIdx.x * 256 + threadIdx.x;
    if (idx >= M * 288) return;
    int m = (int)(idx / 288), c = (int)(idx % 288);
    float v;
    if (c < 256) v = input[(long)m * 256 + c];
    else if (c < 266) v = aux[m * 10 + (c - 256)];
    else if (c == 266) v = sk[m];
    else v = 0.f;
    ushort h = f2b(v);
    xhi[idx] = h;
    if (xlo) xlo[idx] = f2b(v - b2f(h));
}

// ---------------- bf16-act x split-bf16-weight MFMA GEMM (R12) ----------------
// Activations A are plain bf16 (act-lo split DROPPED: the al*bh correction term
// removed -> 2 MFMA per K-tile instead of 3, staging 3 arrays (24KB) not 4).
// Weights keep hi/lo split (static, free at 2 MFMA). Predicted absmax ~1e-3
// (attn path already bf16 internally at absmax 6.1e-5 -> large headroom).
// XCD-aware bijective remap (m204) unchanged.
template <int MODE>
__global__ __launch_bounds__(256, 3) void k_gemm(
    const ushort* __restrict__ Ahi,
    const ushort* __restrict__ Bhi, const ushort* __restrict__ Blo,
    int N, int K,
    float* outF, ushort* outHi,
    const float* __restrict__ bias,
    const float* __restrict__ bng, const float* __restrict__ bnb,
    const float* __restrict__ bnm, const float* __restrict__ bnv,
    const ushort* resHi) {
    __shared__ __align__(16) ushort S[3][128][32];   // Ah, Bh, Bl : 24 KB
    int t = threadIdx.x;
    // XCD swizzle
    int flat = blockIdx.y * gridDim.x + blockIdx.x;
    int nwg = gridDim.x * gridDim.y;
    int q = nwg >> 3, r = nwg & 7;
    int xcd = flat & 7, seq = flat >> 3;
    int wgid = (xcd < r ? xcd * (q + 1) : r * (q + 1) + (xcd - r) * q) + seq;
    int bx = wgid % gridDim.x, by = wgid / gridDim.x;
    int m0 = by * 128, n0 = bx * 128;
    int w = t >> 6, lane = t & 63;
    int wm = w >> 1, wn = w & 1;
    int lo16 = lane & 15, hi4 = lane >> 4;

    const int srow = lane >> 2;
    const int skoff = ((lane & 3) ^ (srow & 3)) * 8;   // elements
    const int slot8 = (hi4 ^ (lo16 & 3)) * 8;

    f32x4 acc[4][4];
    #pragma unroll
    for (int i = 0; i < 4; ++i)
        #pragma unroll
        for (int j = 0; j < 4; ++j) acc[i][j] = f32x4{0.f, 0.f, 0.f, 0.f};

    const int nk = K / 32;
    for (int kt = 0; kt < nk; ++kt) {
        const int kb = kt * 32;
        #pragma unroll
        for (int i = 0; i < 2; ++i) {
            int rg = w * 32 + i * 16;              // wave-uniform row-group base
            long ga = (long)(m0 + rg + srow) * K + kb + skoff;
            long gb = (long)(n0 + rg + srow) * K + kb + skoff;
            gl_lds16(&Ahi[ga], &S[0][rg][0]);
            gl_lds16(&Bhi[gb], &S[1][rg][0]);
            gl_lds16(&Blo[gb], &S[2][rg][0]);
        }
        __syncthreads();
        bf16x8 ah[4], bh[4], bl[4];
        #pragma unroll
        for (int m = 0; m < 4; ++m) {
            int row = wm * 64 + m * 16 + lo16;
            ah[m] = *(const bf16x8*)&S[0][row][slot8];
        }
        #pragma unroll
        for (int n = 0; n < 4; ++n) {
            int col = wn * 64 + n * 16 + lo16;
            bh[n] = *(const bf16x8*)&S[1][col][slot8];
            bl[n] = *(const bf16x8*)&S[2][col][slot8];
        }
        #pragma unroll
        for (int m = 0; m < 4; ++m)
            #pragma unroll
            for (int n = 0; n < 4; ++n) {
                acc[m][n] = __builtin_amdgcn_mfma_f32_16x16x32_bf16(ah[m], bh[n], acc[m][n], 0, 0, 0);
                acc[m][n] = __builtin_amdgcn_mfma_f32_16x16x32_bf16(ah[m], bl[n], acc[m][n], 0, 0, 0);
            }
        __syncthreads();
    }

    #pragma unroll
    for (int n = 0; n < 4; ++n) {
        int gn = n0 + wn * 64 + n * 16 + lo16;
        float bv = bias ? bias[gn] : 0.f;
        float sc = 1.f, sh = 0.f;
        if (MODE >= 1) { sc = bng[gn] * rsqrtf(bnv[gn] + 1e-5f); sh = bnb[gn] - bnm[gn] * sc; }
        #pragma unroll
        for (int m = 0; m < 4; ++m)
            #pragma unroll
            for (int r2 = 0; r2 < 4; ++r2) {
                int gm = m0 + wm * 64 + m * 16 + hi4 * 4 + r2;
                long o = (long)gm * N + gn;
                float v = acc[m][n][r2] + bv;
                if (MODE >= 1) v = fmaxf(v * sc + sh, 0.f);
                if (MODE == 2) v += b2f(resHi[o]);
                if (outF) outF[o] = v;
                if (outHi) outHi[o] = f2b(v);
            }
    }
}

// ---------------- pos (fl2): wave-per-row, vectorized bf16 act loads ----------------
__global__ void k_fl2(const ushort* __restrict__ hA,
                      const float* __restrict__ W, const float* __restrict__ bias,
                      float* __restrict__ pos) {
    int w = threadIdx.x >> 6, lane = threadIdx.x & 63;
    int m = blockIdx.x * 4 + w;
    float a0 = 0.f, a1 = 0.f, a2 = 0.f;
    for (int k0 = lane * 4; k0 < 1024; k0 += 256) {
        long o = (long)m * 1024 + k0;
        u16x4 hv = *(const u16x4*)&hA[o];
        f32x4 w0 = *(const f32x4*)&W[k0];
        f32x4 w1 = *(const f32x4*)&W[1024 + k0];
        f32x4 w2 = *(const f32x4*)&W[2048 + k0];
        #pragma unroll
        for (int e = 0; e < 4; ++e) {
            float x = b2f(hv[e]);
            a0 += x * w0[e]; a1 += x * w1[e]; a2 += x * w2[e];
        }
    }
    #pragma unroll
    for (int off = 32; off; off >>= 1) {
        a0 += __shfl_xor(a0, off, 64);
        a1 += __shfl_xor(a1, off, 64);
        a2 += __shfl_xor(a2, off, 64);
    }
    if (lane == 0) {
        pos[m * 3 + 0] = a0 + bias[0];
        pos[m * 3 + 1] = a1 + bias[1];
        pos[m * 3 + 2] = a2 + bias[2];
    }
}

// ---------------- fused attention (+rel_emb +fl3) per (b,i) block ----------------
// R11 structure kept verbatim (attn is at its structural floor: 600+-90us
// across 7 variants; busy-products invariant). cvt_pk converts, register
// h1/rel prologue, 4-wave-parallel fl3 tail.
// LDS map (40KB):
//   [0,16384)      REL[64][256B pitch], swz byte = j*256 + ((d*2)^((j&15)<<4))
//   [16384,32768)  XS[64][256B pitch], same swz
//   [32768,40960)  HE[64 rows][128B pitch], swz (c*2)^((r&7)<<4)
//   aggF f32[128] @16384, fl3 partials f32[4][36] @16896 (XS dead by then).
__global__ __launch_bounds__(256, 3) void k_attn(
    const float* __restrict__ qkv, const float* __restrict__ posb,
    const ushort* __restrict__ W1b, const ushort* __restrict__ W2b,
    const float* __restrict__ b1, const ushort* __restrict__ pW2b,
    const float* __restrict__ pW1, const float* __restrict__ pb1,
    const float* __restrict__ pb2,
    const float* __restrict__ fl3W, const float* __restrict__ fl3b,
    float* __restrict__ out, long mbase) {
    __shared__ __align__(16) char smem[40960];
    // XCD-aware swizzle: gridDim.x % 8 == 0 always (12800 or 6400)
    int cpx = gridDim.x >> 3;
    int biL = (blockIdx.x & 7) * cpx + (blockIdx.x >> 3);
    int bL = biL / 50;
    int t = threadIdx.x, w = t >> 6, lane = t & 63;
    int lo16 = lane & 15, hi4 = lane >> 4;

    // ---- phase 0a: h1 fragments in registers (row-split, wave-private) ----
    // lane holds h1[jrow][k] for jrow = w*16+lo16, k = kt*32 + hi4*8 + e
    bf16x8 h_a[2];
    {
        const int jrow = w * 16 + lo16;
        const bool jvalid = jrow < 50;
        float pi0 = posb[biL * 3], pi1 = posb[biL * 3 + 1], pi2 = posb[biL * 3 + 2];
        float d0 = 0.f, d1 = 0.f, d2 = 0.f;
        if (jvalid) {
            int pj = (bL * 50 + jrow) * 3;
            d0 = pi0 - posb[pj]; d1 = pi1 - posb[pj + 1]; d2 = pi2 - posb[pj + 2];
        }
        #pragma unroll
        for (int kt = 0; kt < 2; ++kt) {
            float hv[8];
            #pragma unroll
            for (int e = 0; e < 8; ++e) {
                int ke = kt * 32 + hi4 * 8 + e;
                hv[e] = jvalid
                    ? fmaxf(pb1[ke] + pW1[ke * 3] * d0 + pW1[ke * 3 + 1] * d1
                            + pW1[ke * 3 + 2] * d2, 0.f)
                    : 0.f;
            }
            unsigned* hu = (unsigned*)&h_a[kt];
            #pragma unroll
            for (int i = 0; i < 4; ++i) hu[i] = f2b2(hv[2 * i], hv[2 * i + 1]);
        }
    }

    // ---- phase 0b: rel rows for own 16 j (MFMA K=64) -> REL (wave-private) ----
    {
        f32x4 racc[8];
        #pragma unroll
        for (int n = 0; n < 8; ++n) racc[n] = f32x4{0.f, 0.f, 0.f, 0.f};
        #pragma unroll
        for (int kt = 0; kt < 2; ++kt) {
            int k0 = kt * 32 + hi4 * 8;
            #pragma unroll
            for (int n = 0; n < 8; ++n) {
                bf16x8 bv = *(const bf16x8*)&pW2b[(n * 16 + lo16) * 64 + k0];
                racc[n] = __builtin_amdgcn_mfma_f32_16x16x32_bf16(h_a[kt], bv, racc[n], 0, 0, 0);
            }
        }
        int j0 = w * 16 + hi4 * 4;
        #pragma unroll
        for (int n = 0; n < 8; ++n) {
            int col = n * 16 + lo16;
            float pb = pb2[col];
            unsigned p01 = f2b2(racc[n][0] + pb, racc[n][1] + pb);
            unsigned p23 = f2b2(racc[n][2] + pb, racc[n][3] + pb);
            *(ushort*)(smem + (j0 + 0) * 256 + ((col * 2) ^ (((j0 + 0) & 15) << 4))) = (ushort)p01;
            *(ushort*)(smem + (j0 + 1) * 256 + ((col * 2) ^ (((j0 + 1) & 15) << 4))) = (ushort)(p01 >> 16);
            *(ushort*)(smem + (j0 + 2) * 256 + ((col * 2) ^ (((j0 + 2) & 15) << 4))) = (ushort)p23;
            *(ushort*)(smem + (j0 + 3) * 256 + ((col * 2) ^ (((j0 + 3) & 15) << 4))) = (ushort)(p23 >> 16);
        }
    }
    __syncthreads();   // REL complete (X-build reads rows written by other waves)

    // ---- phase 1: X = q_i - k_j + rel -> XS @16K (bf16 swz); rows 50..63 zero ----
    #pragma unroll
    for (int cc = 0; cc < 4; ++cc) {
        int c = cc * 256 + t;
        int row = c >> 4, g = c & 15;
        bf16x8 tv;
        if (row < 50) {
            long kq = (long)biL * 384 + g * 8;
            long kk = (long)(bL * 50 + row) * 384 + 128 + g * 8;
            f32x4 q0 = *(const f32x4*)&qkv[kq];
            f32x4 q1 = *(const f32x4*)&qkv[kq + 4];
            f32x4 k0 = *(const f32x4*)&qkv[kk];
            f32x4 k1 = *(const f32x4*)&qkv[kk + 4];
            bf16x8 rv = *(const bf16x8*)(smem + row * 256 + ((g * 16) ^ ((row & 15) << 4)));
            unsigned* tu = (unsigned*)&tv;
            #pragma unroll
            for (int i = 0; i < 2; ++i)
                tu[i] = f2b2(q0[2 * i] - k0[2 * i] + b2f((ushort)rv[2 * i]),
                             q0[2 * i + 1] - k0[2 * i + 1] + b2f((ushort)rv[2 * i + 1]));
            #pragma unroll
            for (int i = 0; i < 2; ++i)
                tu[2 + i] = f2b2(q1[2 * i] - k1[2 * i] + b2f((ushort)rv[4 + 2 * i]),
                                 q1[2 * i + 1] - k1[2 * i + 1] + b2f((ushort)rv[4 + 2 * i + 1]));
        } else {
            #pragma unroll
            for (int e = 0; e < 8; ++e) tv[e] = 0;
        }
        *(bf16x8*)(smem + 16384 + row * 256 + ((g * 16) ^ ((row & 15) << 4))) = tv;
    }
    __syncthreads();   // XS complete

    // ---- main loop: 8 eighths of H (64 cols each), 2 barriers per e8 ----
    f32x4 acc2[4][2];
    #pragma unroll
    for (int m = 0; m < 4; ++m)
        #pragma unroll
        for (int n = 0; n < 2; ++n) acc2[m][n] = f32x4{0.f, 0.f, 0.f, 0.f};

    for (int e8 = 0; e8 < 8; ++e8) {
        // GEMM1: H[:, wave's 16 cols of e8] over K=128 (bv reused 4x)
        f32x4 acc1[4];
        #pragma unroll
        for (int m = 0; m < 4; ++m) acc1[m] = f32x4{0.f, 0.f, 0.f, 0.f};
        __builtin_amdgcn_s_setprio(1);
        #pragma unroll
        for (int kt = 0; kt < 4; ++kt) {
            int col = e8 * 64 + w * 16 + lo16;
            int k = kt * 32 + hi4 * 8;
            bf16x8 bfv = *(const bf16x8*)&W1b[(long)col * 128 + k];
            #pragma unroll
            for (int m = 0; m < 4; ++m) {
                int row = m * 16 + lo16;
                bf16x8 af = *(const bf16x8*)(smem + 16384 + row * 256 +
                          ((k * 2) ^ ((row & 15) << 4)));
                acc1[m] = __builtin_amdgcn_mfma_f32_16x16x32_bf16(af, bfv, acc1[m], 0, 0, 0);
            }
        }
        __builtin_amdgcn_s_setprio(0);
        __syncthreads();   // prev eighth's GEMM2 reads of HE done
        {
            int ch = w * 16 + lo16;             // local col in [0,64)
            float bv = b1[e8 * 64 + ch];
            int row0 = hi4 * 4;
            #pragma unroll
            for (int m = 0; m < 4; ++m) {
                unsigned p01 = f2b2(fmaxf(acc1[m][0] + bv, 0.f), fmaxf(acc1[m][1] + bv, 0.f));
                unsigned p23 = f2b2(fmaxf(acc1[m][2] + bv, 0.f), fmaxf(acc1[m][3] + bv, 0.f));
                int r0 = m * 16 + row0;
                *(ushort*)(smem + 32768 + (r0 + 0) * 128 + ((ch * 2) ^ (((r0 + 0) & 7) << 4))) = (ushort)p01;
                *(ushort*)(smem + 32768 + (r0 + 1) * 128 + ((ch * 2) ^ (((r0 + 1) & 7) << 4))) = (ushort)(p01 >> 16);
                *(ushort*)(smem + 32768 + (r0 + 2) * 128 + ((ch * 2) ^ (((r0 + 2) & 7) << 4))) = (ushort)p23;
                *(ushort*)(smem + 32768 + (r0 + 3) * 128 + ((ch * 2) ^ (((r0 + 3) & 7) << 4))) = (ushort)(p23 >> 16);
            }
        }
        __syncthreads();
        // GEMM2 partial: K chunk [e8*64, e8*64+64), HE @32K
        for (int kt2 = 0; kt2 < 2; ++kt2) {
            bf16x8 af[4];
            #pragma unroll
            for (int m = 0; m < 4; ++m) {
                int row = m * 16 + lo16;
                af[m] = *(const bf16x8*)(smem + 32768 + row * 128 +
                          (((kt2 * 32 + hi4 * 8) * 2) ^ ((row & 7) << 4)));
            }
            __builtin_amdgcn_s_setprio(1);
            #pragma unroll
            for (int n = 0; n < 2; ++n) {
                int col = w * 32 + n * 16 + lo16;
                int gk = e8 * 64 + kt2 * 32 + hi4 * 8;
                bf16x8 bfv = *(const bf16x8*)&W2b[(long)col * 512 + gk];
                #pragma unroll
                for (int m = 0; m < 4; ++m)
                    acc2[m][n] = __builtin_amdgcn_mfma_f32_16x16x32_bf16(af[m], bfv, acc2[m][n], 0, 0, 0);
            }
            __builtin_amdgcn_s_setprio(0);
        }
    }

    // ---- softmax over j + agg (v_ij = v + rel, rel from REL @0) ----
    float outv[2];
    #pragma unroll
    for (int n = 0; n < 2; ++n) {
        float mx = -1e30f;
        #pragma unroll
        for (int m = 0; m < 4; ++m)
            #pragma unroll
            for (int r = 0; r < 4; ++r) {
                int j = m * 16 + hi4 * 4 + r;
                if (j < 50) mx = fmaxf(mx, acc2[m][n][r]);
            }
        mx = fmaxf(mx, __shfl_xor(mx, 16, 64));
        mx = fmaxf(mx, __shfl_xor(mx, 32, 64));
        float e[4][4];
        float sum = 0.f;
        #pragma unroll
        for (int m = 0; m < 4; ++m)
            #pragma unroll
            for (int r = 0; r < 4; ++r) {
                int j = m * 16 + hi4 * 4 + r;
                float ev = (j < 50) ? __expf(acc2[m][n][r] - mx) : 0.f;
                e[m][r] = ev; sum += ev;
            }
        sum += __shfl_xor(sum, 16, 64);
        sum += __shfl_xor(sum, 32, 64);
        float inv = 1.f / sum;
        int col = w * 32 + n * 16 + lo16;
        float ag = 0.f;
        #pragma unroll
        for (int m = 0; m < 4; ++m)
            #pragma unroll
            for (int r = 0; r < 4; ++r) {
                int j = m * 16 + hi4 * 4 + r;
                if (j < 50) {
                    float rl = b2f(*(const ushort*)(smem + j * 256 +
                                  ((col * 2) ^ ((j & 15) << 4))));
                    float vv = qkv[(long)(bL * 50 + j) * 384 + 256 + col] + rl;
                    ag += e[m][r] * inv * vv;
                }
            }
        ag += __shfl_xor(ag, 16, 64);
        ag += __shfl_xor(ag, 32, 64);
        outv[n] = ag;
    }
    // aggF: each wave writes its own 32-col slice (cols w*32..w*32+32)
    float* aggF = (float*)(smem + 16384);
    float* part = (float*)(smem + 16896);   // f32[4][36]
    if (hi4 == 0) {
        aggF[w * 32 + lo16] = outv[0];
        aggF[w * 32 + 16 + lo16] = outv[1];
    }
    // fl3 partials: wave-local read of OWN aggF slice (same-wave DS ordering,
    // no barrier needed); each wave covers d-quarter [w*32, w*32+32)
    if (lane < 36) {
        const float* wf = &fl3W[lane * 128 + w * 32];
        const float* af = aggF + w * 32;
        float s = 0.f;
        #pragma unroll 8
        for (int d = 0; d < 32; ++d) s += af[d] * wf[d];
        part[w * 36 + lane] = s;
    }
    __syncthreads();

    // fused fl3 + tanh
    if (t < 36) {
        float s = fl3b[t] + part[t] + part[36 + t] + part[72 + t] + part[108 + t];
        out[(mbase + biL) * 36 + t] = tanhf(s);
    }
}

// ---------------- launch ----------------
struct Bufs {
    float *sk, *aux, *qkvF, *posb, *WcF, *bc;
    ushort *xh, *actAh, *actBh;
    ushort *l0Wh, *l0Wl, *resWh, *resWl, *Wch, *Wcl, *aW1b, *aW2b, *pW2b;
};

static size_t plan_ws(char* ws, long MCr, Bufs& B) {
    size_t off = 0;
    auto alloc = [&](size_t n) { char* p = ws + off; off += (n + 255) & ~(size_t)255; return p; };
    B.sk    = (float*) alloc(12800L * 4);
    B.aux   = (float*) alloc(128000L * 4);
    B.xh    = (ushort*)alloc((size_t)MCr * 288 * 2);
    B.actAh = (ushort*)alloc((size_t)MCr * 1024 * 2);
    B.actBh = (ushort*)alloc((size_t)MCr * 1024 * 2);
    B.qkvF  = (float*) alloc((size_t)MCr * 384 * 4);
    B.posb  = (float*) alloc((size_t)MCr * 3 * 4);
    B.l0Wh  = (ushort*)alloc(1024L * 288 * 2);
    B.l0Wl  = (ushort*)alloc(1024L * 288 * 2);
    B.resWh = (ushort*)alloc(6144L * 1024 * 2);
    B.resWl = (ushort*)alloc(6144L * 1024 * 2);
    B.WcF   = (float*) alloc(384L * 1024 * 4);
    B.Wch   = (ushort*)alloc(384L * 1024 * 2);
    B.Wcl   = (ushort*)alloc(384L * 1024 * 2);
    B.bc    = (float*) alloc(384L * 4);
    B.aW1b  = (ushort*)alloc(512L * 128 * 2);
    B.aW2b  = (ushort*)alloc(128L * 512 * 2);
    B.pW2b  = (ushort*)alloc(128L * 64 * 2);
    return off;
}

extern "C" void kernel_launch(void* const* d_in, const int* in_sizes, int n_in,
                              void* d_out, int out_size, void* d_ws, size_t ws_size,
                              hipStream_t stream) {
    (void)in_sizes; (void)n_in;
    const float* input  = (const float*)d_in[0];
    const float* fskel  = (const float*)d_in[1];
    const float* noise  = (const float*)d_in[2];
    const float* firstW = (const float*)d_in[3];
    const float* firstB = (const float*)d_in[4];
    const float* gWih   = (const float*)d_in[5];
    const float* gWhh   = (const float*)d_in[6];
    const float* gbih   = (const float*)d_in[7];
    const float* gbhh   = (const float*)d_in[8];
    const float* l0W    = (const float*)d_in[9];
    const float* l0b    = (const float*)d_in[10];
    const float* resW   = (const float*)d_in[11];
    const float* resB   = (const float*)d_in[12];
    const float* bnG    = (const float*)d_in[13];
    const float* bnB    = (const float*)d_in[14];
    const float* bnM    = (const float*)d_in[15];
    const float* bnV    = (const float*)d_in[16];
    const float* fl1W   = (const float*)d_in[17];
    const float* fl1b   = (const float*)d_in[18];
    const float* fl2W   = (const float*)d_in[19];
    const float* fl2b   = (const float*)d_in[20];
    const float* fl3W   = (const float*)d_in[21];
    const float* fl3b   = (const float*)d_in[22];
    const float* qkvW   = (const float*)d_in[23];
    const float* pW1    = (const float*)d_in[24];
    const float* pb1    = (const float*)d_in[25];
    const float* pW2    = (const float*)d_in[26];
    const float* pb2    = (const float*)d_in[27];
    const float* aW1    = (const float*)d_in[28];
    const float* ab1    = (const float*)d_in[29];
    const float* aW2    = (const float*)d_in[30];
    float* out = (float*)d_out;

    char* ws = (char*)d_ws;
    Bufs B;
    long MCr = 12800;                         // single chunk if it fits
    if (plan_ws(ws, MCr, B) > ws_size) {
        MCr = 6400;
        if (plan_ws(ws, MCr, B) > ws_size) {  // diagnostic: clean zero output
            hipMemsetAsync(d_out, 0, (size_t)out_size * sizeof(float), stream);
            return;
        }
    }
    const int nchunks = (int)(12800 / MCr);

    // one-time prep
    k_split<<<1152, 256, 0, stream>>>(l0W, B.l0Wh, B.l0Wl, 1024, 267, 288);
    k_split<<<8192, 256, 0, stream>>>(resW, B.resWh, B.resWl, 6144, 1024, 1024);
    k_wc<<<1536, 256, 0, stream>>>(qkvW, fl1W, fl1b, B.WcF, B.bc);
    k_split<<<1536, 256, 0, stream>>>(B.WcF, B.Wch, B.Wcl, 384, 1024, 1024);
    k_split<<<256, 256, 0, stream>>>(aW1, B.aW1b, nullptr, 512, 128, 128);
    k_split<<<256, 256, 0, stream>>>(aW2, B.aW2b, nullptr, 128, 512, 512);
    k_split<<<32, 256, 0, stream>>>(pW2, B.pW2b, nullptr, 128, 64, 64);
    k_sk<<<50, 256, 0, stream>>>(fskel, firstW, firstB, B.sk);
    k_gru<<<256, 64, 0, stream>>>(noise, gWih, gWhh, gbih, gbhh, B.aux);

    for (int c = 0; c < nchunks; ++c) {
        long mbase = (long)c * MCr;
        int xb_grid = (int)((MCr * 288 + 255) / 256);
        k_xbuild<<<xb_grid, 256, 0, stream>>>(input + mbase * 256, B.aux + mbase * 10,
                                              B.sk + mbase, B.xh, nullptr, MCr);
        dim3 gt(8, (unsigned)(MCr / 128));
        k_gemm<0><<<gt, 256, 0, stream>>>(B.xh, B.l0Wh, B.l0Wl, 1024, 288,
            nullptr, B.actAh, l0b, nullptr, nullptr, nullptr, nullptr, nullptr);
        for (int blk = 0; blk < 3; ++blk) {
            int j0 = blk * 2, j1 = blk * 2 + 1;
            k_gemm<1><<<gt, 256, 0, stream>>>(B.actAh,
                B.resWh + (size_t)j0 * 1024 * 1024, B.resWl + (size_t)j0 * 1024 * 1024,
                1024, 1024, nullptr, B.actBh, resB + j0 * 1024,
                bnG + j0 * 1024, bnB + j0 * 1024, bnM + j0 * 1024, bnV + j0 * 1024,
                nullptr);
            k_gemm<2><<<gt, 256, 0, stream>>>(B.actBh,
                B.resWh + (size_t)j1 * 1024 * 1024, B.resWl + (size_t)j1 * 1024 * 1024,
                1024, 1024, nullptr, B.actAh, resB + j1 * 1024,
                bnG + j1 * 1024, bnB + j1 * 1024, bnM + j1 * 1024, bnV + j1 * 1024,
                B.actAh);
        }
        dim3 gq(3, (unsigned)(MCr / 128));
        k_gemm<0><<<gq, 256, 0, stream>>>(B.actAh, B.Wch, B.Wcl, 384, 1024,
            B.qkvF, nullptr, B.bc, nullptr, nullptr, nullptr, nullptr, nullptr);
        k_fl2<<<(int)(MCr / 4), 256, 0, stream>>>(B.actAh, fl2W, fl2b, B.posb);
        k_attn<<<(int)MCr, 256, 0, stream>>>(B.qkvF, B.posb, B.aW1b, B.aW2b, ab1, B.pW2b,
                                             pW1, pb1, pb2, fl3W, fl3b, out, mbase);
    }
}

// Round 8
// 1020.227 us; speedup vs baseline: 1.6001x; 1.2007x over previous
//
#include <hip/hip_runtime.h>

typedef __attribute__((ext_vector_type(8))) short bf16x8;
typedef __attribute__((ext_vector_type(4))) float f32x4;
typedef __attribute__((ext_vector_type(4))) ushort u16x4;

// HW bf16 convert (RNE), gfx950 v_cvt_pk_bf16_f32: 2 floats -> 1 VGPR (1 op)
__device__ __forceinline__ unsigned f2b2(float lo, float hi) {
    unsigned r;
    asm("v_cvt_pk_bf16_f32 %0, %1, %2" : "=v"(r) : "v"(lo), "v"(hi));
    return r;
}
__device__ __forceinline__ ushort f2b(float v) {
    return (ushort)f2b2(v, v);
}
__device__ __forceinline__ float b2f(ushort b) {
    union { float f; unsigned u; } x; x.u = ((unsigned)b) << 16; return x.f;
}

// async global->LDS 16B per lane; LDS dest = wave-uniform base + lane*16
__device__ __forceinline__ void gl_lds16(const void* g, void* l) {
    __builtin_amdgcn_global_load_lds(
        (__attribute__((address_space(1))) void*)(g),
        (__attribute__((address_space(3))) void*)(l), 16, 0, 0);
}

// ---------------- prep kernels ----------------

__global__ void k_split(const float* __restrict__ src, ushort* __restrict__ hi,
                        ushort* __restrict__ lo, int rows, int K, int Kpad) {
    long total = (long)rows * Kpad;
    for (long idx = (long)blockIdx.x * 256 + threadIdx.x; idx < total;
         idx += (long)gridDim.x * 256) {
        int r = (int)(idx / Kpad), c = (int)(idx % Kpad);
        float v = (c < K) ? src[(long)r * K + c] : 0.f;
        ushort h = f2b(v);
        hi[idx] = h;
        if (lo) lo[idx] = f2b(v - b2f(h));
    }
}

// Wc[n][k] = sum_d qkvW[n][d] * fl1W[d][k];  bc[n] = sum_d qkvW[n][d] * fl1b[d]
__global__ void k_wc(const float* __restrict__ qkvW, const float* __restrict__ fl1W,
                     const float* __restrict__ fl1b, float* __restrict__ Wc,
                     float* __restrict__ bc) {
    int idx = blockIdx.x * 256 + threadIdx.x;
    if (idx >= 384 * 1024) return;
    int n = idx >> 10, k = idx & 1023;
    float s = 0.f;
    #pragma unroll 8
    for (int d = 0; d < 128; ++d) s += qkvW[n * 128 + d] * fl1W[d * 1024 + k];
    Wc[idx] = s;
    if (k == 0) {
        float sb = 0.f;
        #pragma unroll 8
        for (int d = 0; d < 128; ++d) sb += qkvW[n * 128 + d] * fl1b[d];
        bc[n] = sb;
    }
}

__global__ void k_sk(const float* __restrict__ fs, const float* __restrict__ fW,
                     const float* __restrict__ fb, float* __restrict__ sk) {
    int m = blockIdx.x * 256 + threadIdx.x;
    if (m >= 12800) return;
    int b = m / 50, i = m % 50;
    float s = fb[i];
    #pragma unroll 4
    for (int c = 0; c < 36; ++c) s += fs[b * 36 + c] * fW[i * 36 + c];
    sk[m] = s;
}

// GRU(10->10): one wave (=one block of 64) per batch element -> 256 CUs covered
__global__ void k_gru(const float* __restrict__ noise, const float* __restrict__ Wih,
                      const float* __restrict__ Whh, const float* __restrict__ bih,
                      const float* __restrict__ bhh, float* __restrict__ aux) {
    int lane = threadIdx.x & 63;
    int b = blockIdx.x;
    if (b >= 256) return;
    float wih[10] = {}, whh[10] = {};
    float bi = 0.f, bh = 0.f;
    if (lane < 30) {
        #pragma unroll
        for (int c = 0; c < 10; ++c) { wih[c] = Wih[lane * 10 + c]; whh[c] = Whh[lane * 10 + c]; }
        bi = bih[lane]; bh = bhh[lane];
    }
    float h = 0.f;
    for (int t = 0; t < 50; ++t) {
        float xr = (lane < 10) ? noise[(b * 50 + t) * 10 + lane] : 0.f;
        float gi = bi, gh = bh;
        #pragma unroll
        for (int c = 0; c < 10; ++c) {
            float xc = __shfl(xr, c, 64);
            float hc = __shfl(h, c, 64);
            gi += wih[c] * xc; gh += whh[c] * hc;
        }
        float siz = __shfl(gi, lane + 10, 64), shz = __shfl(gh, lane + 10, 64);
        float sin_ = __shfl(gi, lane + 20, 64), shn = __shfl(gh, lane + 20, 64);
        float r = 1.f / (1.f + expf(-(gi + gh)));
        float z = 1.f / (1.f + expf(-(siz + shz)));
        float n = tanhf(sin_ + r * shn);
        float hn = (1.f - z) * n + z * h;
        if (lane < 10) { h = hn; aux[(b * 50 + t) * 10 + lane] = tanhf(hn); }
    }
}

__global__ void k_xbuild(const float* __restrict__ input, const float* __restrict__ aux,
                         const float* __restrict__ sk, ushort* __restrict__ xhi,
                         long M) {
    long idx = (long)blockIdx.x * 256 + threadIdx.x;
    if (idx >= M * 288) return;
    int m = (int)(idx / 288), c = (int)(idx % 288);
    float v;
    if (c < 256) v = input[(long)m * 256 + c];
    else if (c < 266) v = aux[m * 10 + (c - 256)];
    else if (c == 266) v = sk[m];
    else v = 0.f;
    xhi[idx] = f2b(v);
}

// ---------------- plain-bf16 MFMA GEMM (R13) ----------------
// Both activations AND weights plain bf16 (weight-lo split dropped: 1 MFMA
// per K-tile, staging 2 arrays / 16KB). Falsifier: absmax (predicted ~1e-3;
// error floor stayed 6.1e-5 through both prior precision cuts -> headroom).
// XCD-aware bijective remap (m204) unchanged.
template <int MODE>
__global__ __launch_bounds__(256, 3) void k_gemm(
    const ushort* __restrict__ Ahi,
    const ushort* __restrict__ Bhi,
    int N, int K,
    float* outF, ushort* outHi,
    const float* __restrict__ bias,
    const float* __restrict__ bng, const float* __restrict__ bnb,
    const float* __restrict__ bnm, const float* __restrict__ bnv,
    const ushort* resHi) {
    __shared__ __align__(16) ushort S[2][128][32];   // Ah, Bh : 16 KB
    int t = threadIdx.x;
    // XCD swizzle
    int flat = blockIdx.y * gridDim.x + blockIdx.x;
    int nwg = gridDim.x * gridDim.y;
    int q = nwg >> 3, r = nwg & 7;
    int xcd = flat & 7, seq = flat >> 3;
    int wgid = (xcd < r ? xcd * (q + 1) : r * (q + 1) + (xcd - r) * q) + seq;
    int bx = wgid % gridDim.x, by = wgid / gridDim.x;
    int m0 = by * 128, n0 = bx * 128;
    int w = t >> 6, lane = t & 63;
    int wm = w >> 1, wn = w & 1;
    int lo16 = lane & 15, hi4 = lane >> 4;

    const int srow = lane >> 2;
    const int skoff = ((lane & 3) ^ (srow & 3)) * 8;   // elements
    const int slot8 = (hi4 ^ (lo16 & 3)) * 8;

    f32x4 acc[4][4];
    #pragma unroll
    for (int i = 0; i < 4; ++i)
        #pragma unroll
        for (int j = 0; j < 4; ++j) acc[i][j] = f32x4{0.f, 0.f, 0.f, 0.f};

    const int nk = K / 32;
    for (int kt = 0; kt < nk; ++kt) {
        const int kb = kt * 32;
        #pragma unroll
        for (int i = 0; i < 2; ++i) {
            int rg = w * 32 + i * 16;              // wave-uniform row-group base
            long ga = (long)(m0 + rg + srow) * K + kb + skoff;
            long gb = (long)(n0 + rg + srow) * K + kb + skoff;
            gl_lds16(&Ahi[ga], &S[0][rg][0]);
            gl_lds16(&Bhi[gb], &S[1][rg][0]);
        }
        __syncthreads();
        bf16x8 ah[4], bh[4];
        #pragma unroll
        for (int m = 0; m < 4; ++m) {
            int row = wm * 64 + m * 16 + lo16;
            ah[m] = *(const bf16x8*)&S[0][row][slot8];
        }
        #pragma unroll
        for (int n = 0; n < 4; ++n) {
            int col = wn * 64 + n * 16 + lo16;
            bh[n] = *(const bf16x8*)&S[1][col][slot8];
        }
        #pragma unroll
        for (int m = 0; m < 4; ++m)
            #pragma unroll
            for (int n = 0; n < 4; ++n)
                acc[m][n] = __builtin_amdgcn_mfma_f32_16x16x32_bf16(ah[m], bh[n], acc[m][n], 0, 0, 0);
        __syncthreads();
    }

    #pragma unroll
    for (int n = 0; n < 4; ++n) {
        int gn = n0 + wn * 64 + n * 16 + lo16;
        float bv = bias ? bias[gn] : 0.f;
        float sc = 1.f, sh = 0.f;
        if (MODE >= 1) { sc = bng[gn] * rsqrtf(bnv[gn] + 1e-5f); sh = bnb[gn] - bnm[gn] * sc; }
        #pragma unroll
        for (int m = 0; m < 4; ++m)
            #pragma unroll
            for (int r2 = 0; r2 < 4; ++r2) {
                int gm = m0 + wm * 64 + m * 16 + hi4 * 4 + r2;
                long o = (long)gm * N + gn;
                float v = acc[m][n][r2] + bv;
                if (MODE >= 1) v = fmaxf(v * sc + sh, 0.f);
                if (MODE == 2) v += b2f(resHi[o]);
                if (outF) outF[o] = v;
                if (outHi) outHi[o] = f2b(v);
            }
    }
}

// ---------------- pos (fl2): wave-per-row, vectorized bf16 act loads ----------------
__global__ void k_fl2(const ushort* __restrict__ hA,
                      const float* __restrict__ W, const float* __restrict__ bias,
                      float* __restrict__ pos) {
    int w = threadIdx.x >> 6, lane = threadIdx.x & 63;
    int m = blockIdx.x * 4 + w;
    float a0 = 0.f, a1 = 0.f, a2 = 0.f;
    for (int k0 = lane * 4; k0 < 1024; k0 += 256) {
        long o = (long)m * 1024 + k0;
        u16x4 hv = *(const u16x4*)&hA[o];
        f32x4 w0 = *(const f32x4*)&W[k0];
        f32x4 w1 = *(const f32x4*)&W[1024 + k0];
        f32x4 w2 = *(const f32x4*)&W[2048 + k0];
        #pragma unroll
        for (int e = 0; e < 4; ++e) {
            float x = b2f(hv[e]);
            a0 += x * w0[e]; a1 += x * w1[e]; a2 += x * w2[e];
        }
    }
    #pragma unroll
    for (int off = 32; off; off >>= 1) {
        a0 += __shfl_xor(a0, off, 64);
        a1 += __shfl_xor(a1, off, 64);
        a2 += __shfl_xor(a2, off, 64);
    }
    if (lane == 0) {
        pos[m * 3 + 0] = a0 + bias[0];
        pos[m * 3 + 1] = a1 + bias[1];
        pos[m * 3 + 2] = a2 + bias[2];
    }
}

// ---------------- fused attention (+rel_emb +fl3) per (b,i) block ----------------
// R11 structure kept verbatim (attn is at its structural floor: 600+-90us
// across 7 variants; busy-products invariant). cvt_pk converts, register
// h1/rel prologue, 4-wave-parallel fl3 tail.
// LDS map (40KB):
//   [0,16384)      REL[64][256B pitch], swz byte = j*256 + ((d*2)^((j&15)<<4))
//   [16384,32768)  XS[64][256B pitch], same swz
//   [32768,40960)  HE[64 rows][128B pitch], swz (c*2)^((r&7)<<4)
//   aggF f32[128] @16384, fl3 partials f32[4][36] @16896 (XS dead by then).
__global__ __launch_bounds__(256, 3) void k_attn(
    const float* __restrict__ qkv, const float* __restrict__ posb,
    const ushort* __restrict__ W1b, const ushort* __restrict__ W2b,
    const float* __restrict__ b1, const ushort* __restrict__ pW2b,
    const float* __restrict__ pW1, const float* __restrict__ pb1,
    const float* __restrict__ pb2,
    const float* __restrict__ fl3W, const float* __restrict__ fl3b,
    float* __restrict__ out, long mbase) {
    __shared__ __align__(16) char smem[40960];
    // XCD-aware swizzle: gridDim.x % 8 == 0 always (12800 or 6400)
    int cpx = gridDim.x >> 3;
    int biL = (blockIdx.x & 7) * cpx + (blockIdx.x >> 3);
    int bL = biL / 50;
    int t = threadIdx.x, w = t >> 6, lane = t & 63;
    int lo16 = lane & 15, hi4 = lane >> 4;

    // ---- phase 0a: h1 fragments in registers (row-split, wave-private) ----
    // lane holds h1[jrow][k] for jrow = w*16+lo16, k = kt*32 + hi4*8 + e
    bf16x8 h_a[2];
    {
        const int jrow = w * 16 + lo16;
        const bool jvalid = jrow < 50;
        float pi0 = posb[biL * 3], pi1 = posb[biL * 3 + 1], pi2 = posb[biL * 3 + 2];
        float d0 = 0.f, d1 = 0.f, d2 = 0.f;
        if (jvalid) {
            int pj = (bL * 50 + jrow) * 3;
            d0 = pi0 - posb[pj]; d1 = pi1 - posb[pj + 1]; d2 = pi2 - posb[pj + 2];
        }
        #pragma unroll
        for (int kt = 0; kt < 2; ++kt) {
            float hv[8];
            #pragma unroll
            for (int e = 0; e < 8; ++e) {
                int ke = kt * 32 + hi4 * 8 + e;
                hv[e] = jvalid
                    ? fmaxf(pb1[ke] + pW1[ke * 3] * d0 + pW1[ke * 3 + 1] * d1
                            + pW1[ke * 3 + 2] * d2, 0.f)
                    : 0.f;
            }
            unsigned* hu = (unsigned*)&h_a[kt];
            #pragma unroll
            for (int i = 0; i < 4; ++i) hu[i] = f2b2(hv[2 * i], hv[2 * i + 1]);
        }
    }

    // ---- phase 0b: rel rows for own 16 j (MFMA K=64) -> REL (wave-private) ----
    {
        f32x4 racc[8];
        #pragma unroll
        for (int n = 0; n < 8; ++n) racc[n] = f32x4{0.f, 0.f, 0.f, 0.f};
        #pragma unroll
        for (int kt = 0; kt < 2; ++kt) {
            int k0 = kt * 32 + hi4 * 8;
            #pragma unroll
            for (int n = 0; n < 8; ++n) {
                bf16x8 bv = *(const bf16x8*)&pW2b[(n * 16 + lo16) * 64 + k0];
                racc[n] = __builtin_amdgcn_mfma_f32_16x16x32_bf16(h_a[kt], bv, racc[n], 0, 0, 0);
            }
        }
        int j0 = w * 16 + hi4 * 4;
        #pragma unroll
        for (int n = 0; n < 8; ++n) {
            int col = n * 16 + lo16;
            float pb = pb2[col];
            unsigned p01 = f2b2(racc[n][0] + pb, racc[n][1] + pb);
            unsigned p23 = f2b2(racc[n][2] + pb, racc[n][3] + pb);
            *(ushort*)(smem + (j0 + 0) * 256 + ((col * 2) ^ (((j0 + 0) & 15) << 4))) = (ushort)p01;
            *(ushort*)(smem + (j0 + 1) * 256 + ((col * 2) ^ (((j0 + 1) & 15) << 4))) = (ushort)(p01 >> 16);
            *(ushort*)(smem + (j0 + 2) * 256 + ((col * 2) ^ (((j0 + 2) & 15) << 4))) = (ushort)p23;
            *(ushort*)(smem + (j0 + 3) * 256 + ((col * 2) ^ (((j0 + 3) & 15) << 4))) = (ushort)(p23 >> 16);
        }
    }
    __syncthreads();   // REL complete (X-build reads rows written by other waves)

    // ---- phase 1: X = q_i - k_j + rel -> XS @16K (bf16 swz); rows 50..63 zero ----
    #pragma unroll
    for (int cc = 0; cc < 4; ++cc) {
        int c = cc * 256 + t;
        int row = c >> 4, g = c & 15;
        bf16x8 tv;
        if (row < 50) {
            long kq = (long)biL * 384 + g * 8;
            long kk = (long)(bL * 50 + row) * 384 + 128 + g * 8;
            f32x4 q0 = *(const f32x4*)&qkv[kq];
            f32x4 q1 = *(const f32x4*)&qkv[kq + 4];
            f32x4 k0 = *(const f32x4*)&qkv[kk];
            f32x4 k1 = *(const f32x4*)&qkv[kk + 4];
            bf16x8 rv = *(const bf16x8*)(smem + row * 256 + ((g * 16) ^ ((row & 15) << 4)));
            unsigned* tu = (unsigned*)&tv;
            #pragma unroll
            for (int i = 0; i < 2; ++i)
                tu[i] = f2b2(q0[2 * i] - k0[2 * i] + b2f((ushort)rv[2 * i]),
                             q0[2 * i + 1] - k0[2 * i + 1] + b2f((ushort)rv[2 * i + 1]));
            #pragma unroll
            for (int i = 0; i < 2; ++i)
                tu[2 + i] = f2b2(q1[2 * i] - k1[2 * i] + b2f((ushort)rv[4 + 2 * i]),
                                 q1[2 * i + 1] - k1[2 * i + 1] + b2f((ushort)rv[4 + 2 * i + 1]));
        } else {
            #pragma unroll
            for (int e = 0; e < 8; ++e) tv[e] = 0;
        }
        *(bf16x8*)(smem + 16384 + row * 256 + ((g * 16) ^ ((row & 15) << 4))) = tv;
    }
    __syncthreads();   // XS complete

    // ---- main loop: 8 eighths of H (64 cols each), 2 barriers per e8 ----
    f32x4 acc2[4][2];
    #pragma unroll
    for (int m = 0; m < 4; ++m)
        #pragma unroll
        for (int n = 0; n < 2; ++n) acc2[m][n] = f32x4{0.f, 0.f, 0.f, 0.f};

    for (int e8 = 0; e8 < 8; ++e8) {
        // GEMM1: H[:, wave's 16 cols of e8] over K=128 (bv reused 4x)
        f32x4 acc1[4];
        #pragma unroll
        for (int m = 0; m < 4; ++m) acc1[m] = f32x4{0.f, 0.f, 0.f, 0.f};
        __builtin_amdgcn_s_setprio(1);
        #pragma unroll
        for (int kt = 0; kt < 4; ++kt) {
            int col = e8 * 64 + w * 16 + lo16;
            int k = kt * 32 + hi4 * 8;
            bf16x8 bfv = *(const bf16x8*)&W1b[(long)col * 128 + k];
            #pragma unroll
            for (int m = 0; m < 4; ++m) {
                int row = m * 16 + lo16;
                bf16x8 af = *(const bf16x8*)(smem + 16384 + row * 256 +
                          ((k * 2) ^ ((row & 15) << 4)));
                acc1[m] = __builtin_amdgcn_mfma_f32_16x16x32_bf16(af, bfv, acc1[m], 0, 0, 0);
            }
        }
        __builtin_amdgcn_s_setprio(0);
        __syncthreads();   // prev eighth's GEMM2 reads of HE done
        {
            int ch = w * 16 + lo16;             // local col in [0,64)
            float bv = b1[e8 * 64 + ch];
            int row0 = hi4 * 4;
            #pragma unroll
            for (int m = 0; m < 4; ++m) {
                unsigned p01 = f2b2(fmaxf(acc1[m][0] + bv, 0.f), fmaxf(acc1[m][1] + bv, 0.f));
                unsigned p23 = f2b2(fmaxf(acc1[m][2] + bv, 0.f), fmaxf(acc1[m][3] + bv, 0.f));
                int r0 = m * 16 + row0;
                *(ushort*)(smem + 32768 + (r0 + 0) * 128 + ((ch * 2) ^ (((r0 + 0) & 7) << 4))) = (ushort)p01;
                *(ushort*)(smem + 32768 + (r0 + 1) * 128 + ((ch * 2) ^ (((r0 + 1) & 7) << 4))) = (ushort)(p01 >> 16);
                *(ushort*)(smem + 32768 + (r0 + 2) * 128 + ((ch * 2) ^ (((r0 + 2) & 7) << 4))) = (ushort)p23;
                *(ushort*)(smem + 32768 + (r0 + 3) * 128 + ((ch * 2) ^ (((r0 + 3) & 7) << 4))) = (ushort)(p23 >> 16);
            }
        }
        __syncthreads();
        // GEMM2 partial: K chunk [e8*64, e8*64+64), HE @32K
        for (int kt2 = 0; kt2 < 2; ++kt2) {
            bf16x8 af[4];
            #pragma unroll
            for (int m = 0; m < 4; ++m) {
                int row = m * 16 + lo16;
                af[m] = *(const bf16x8*)(smem + 32768 + row * 128 +
                          (((kt2 * 32 + hi4 * 8) * 2) ^ ((row & 7) << 4)));
            }
            __builtin_amdgcn_s_setprio(1);
            #pragma unroll
            for (int n = 0; n < 2; ++n) {
                int col = w * 32 + n * 16 + lo16;
                int gk = e8 * 64 + kt2 * 32 + hi4 * 8;
                bf16x8 bfv = *(const bf16x8*)&W2b[(long)col * 512 + gk];
                #pragma unroll
                for (int m = 0; m < 4; ++m)
                    acc2[m][n] = __builtin_amdgcn_mfma_f32_16x16x32_bf16(af[m], bfv, acc2[m][n], 0, 0, 0);
            }
            __builtin_amdgcn_s_setprio(0);
        }
    }

    // ---- softmax over j + agg (v_ij = v + rel, rel from REL @0) ----
    float outv[2];
    #pragma unroll
    for (int n = 0; n < 2; ++n) {
        float mx = -1e30f;
        #pragma unroll
        for (int m = 0; m < 4; ++m)
            #pragma unroll
            for (int r = 0; r < 4; ++r) {
                int j = m * 16 + hi4 * 4 + r;
                if (j < 50) mx = fmaxf(mx, acc2[m][n][r]);
            }
        mx = fmaxf(mx, __shfl_xor(mx, 16, 64));
        mx = fmaxf(mx, __shfl_xor(mx, 32, 64));
        float e[4][4];
        float sum = 0.f;
        #pragma unroll
        for (int m = 0; m < 4; ++m)
            #pragma unroll
            for (int r = 0; r < 4; ++r) {
                int j = m * 16 + hi4 * 4 + r;
                float ev = (j < 50) ? __expf(acc2[m][n][r] - mx) : 0.f;
                e[m][r] = ev; sum += ev;
            }
        sum += __shfl_xor(sum, 16, 64);
        sum += __shfl_xor(sum, 32, 64);
        float inv = 1.f / sum;
        int col = w * 32 + n * 16 + lo16;
        float ag = 0.f;
        #pragma unroll
        for (int m = 0; m < 4; ++m)
            #pragma unroll
            for (int r = 0; r < 4; ++r) {
                int j = m * 16 + hi4 * 4 + r;
                if (j < 50) {
                    float rl = b2f(*(const ushort*)(smem + j * 256 +
                                  ((col * 2) ^ ((j & 15) << 4))));
                    float vv = qkv[(long)(bL * 50 + j) * 384 + 256 + col] + rl;
                    ag += e[m][r] * inv * vv;
                }
            }
        ag += __shfl_xor(ag, 16, 64);
        ag += __shfl_xor(ag, 32, 64);
        outv[n] = ag;
    }
    // aggF: each wave writes its own 32-col slice (cols w*32..w*32+32)
    float* aggF = (float*)(smem + 16384);
    float* part = (float*)(smem + 16896);   // f32[4][36]
    if (hi4 == 0) {
        aggF[w * 32 + lo16] = outv[0];
        aggF[w * 32 + 16 + lo16] = outv[1];
    }
    // fl3 partials: wave-local read of OWN aggF slice (same-wave DS ordering,
    // no barrier needed); each wave covers d-quarter [w*32, w*32+32)
    if (lane < 36) {
        const float* wf = &fl3W[lane * 128 + w * 32];
        const float* af = aggF + w * 32;
        float s = 0.f;
        #pragma unroll 8
        for (int d = 0; d < 32; ++d) s += af[d] * wf[d];
        part[w * 36 + lane] = s;
    }
    __syncthreads();

    // fused fl3 + tanh
    if (t < 36) {
        float s = fl3b[t] + part[t] + part[36 + t] + part[72 + t] + part[108 + t];
        out[(mbase + biL) * 36 + t] = tanhf(s);
    }
}

// ---------------- launch ----------------
struct Bufs {
    float *sk, *aux, *qkvF, *posb, *WcF, *bc;
    ushort *xh, *actAh, *actBh;
    ushort *l0Wh, *resWh, *Wch, *aW1b, *aW2b, *pW2b;
};

static size_t plan_ws(char* ws, long MCr, Bufs& B) {
    size_t off = 0;
    auto alloc = [&](size_t n) { char* p = ws + off; off += (n + 255) & ~(size_t)255; return p; };
    B.sk    = (float*) alloc(12800L * 4);
    B.aux   = (float*) alloc(128000L * 4);
    B.xh    = (ushort*)alloc((size_t)MCr * 288 * 2);
    B.actAh = (ushort*)alloc((size_t)MCr * 1024 * 2);
    B.actBh = (ushort*)alloc((size_t)MCr * 1024 * 2);
    B.qkvF  = (float*) alloc((size_t)MCr * 384 * 4);
    B.posb  = (float*) alloc((size_t)MCr * 3 * 4);
    B.l0Wh  = (ushort*)alloc(1024L * 288 * 2);
    B.resWh = (ushort*)alloc(6144L * 1024 * 2);
    B.WcF   = (float*) alloc(384L * 1024 * 4);
    B.Wch   = (ushort*)alloc(384L * 1024 * 2);
    B.bc    = (float*) alloc(384L * 4);
    B.aW1b  = (ushort*)alloc(512L * 128 * 2);
    B.aW2b  = (ushort*)alloc(128L * 512 * 2);
    B.pW2b  = (ushort*)alloc(128L * 64 * 2);
    return off;
}

extern "C" void kernel_launch(void* const* d_in, const int* in_sizes, int n_in,
                              void* d_out, int out_size, void* d_ws, size_t ws_size,
                              hipStream_t stream) {
    (void)in_sizes; (void)n_in;
    const float* input  = (const float*)d_in[0];
    const float* fskel  = (const float*)d_in[1];
    const float* noise  = (const float*)d_in[2];
    const float* firstW = (const float*)d_in[3];
    const float* firstB = (const float*)d_in[4];
    const float* gWih   = (const float*)d_in[5];
    const float* gWhh   = (const float*)d_in[6];
    const float* gbih   = (const float*)d_in[7];
    const float* gbhh   = (const float*)d_in[8];
    const float* l0W    = (const float*)d_in[9];
    const float* l0b    = (const float*)d_in[10];
    const float* resW   = (const float*)d_in[11];
    const float* resB   = (const float*)d_in[12];
    const float* bnG    = (const float*)d_in[13];
    const float* bnB    = (const float*)d_in[14];
    const float* bnM    = (const float*)d_in[15];
    const float* bnV    = (const float*)d_in[16];
    const float* fl1W   = (const float*)d_in[17];
    const float* fl1b   = (const float*)d_in[18];
    const float* fl2W   = (const float*)d_in[19];
    const float* fl2b   = (const float*)d_in[20];
    const float* fl3W   = (const float*)d_in[21];
    const float* fl3b   = (const float*)d_in[22];
    const float* qkvW   = (const float*)d_in[23];
    const float* pW1    = (const float*)d_in[24];
    const float* pb1    = (const float*)d_in[25];
    const float* pW2    = (const float*)d_in[26];
    const float* pb2    = (const float*)d_in[27];
    const float* aW1    = (const float*)d_in[28];
    const float* ab1    = (const float*)d_in[29];
    const float* aW2    = (const float*)d_in[30];
    float* out = (float*)d_out;

    char* ws = (char*)d_ws;
    Bufs B;
    long MCr = 12800;                         // single chunk if it fits
    if (plan_ws(ws, MCr, B) > ws_size) {
        MCr = 6400;
        if (plan_ws(ws, MCr, B) > ws_size) {  // diagnostic: clean zero output
            hipMemsetAsync(d_out, 0, (size_t)out_size * sizeof(float), stream);
            return;
        }
    }
    const int nchunks = (int)(12800 / MCr);

    // one-time prep
    k_split<<<1152, 256, 0, stream>>>(l0W, B.l0Wh, nullptr, 1024, 267, 288);
    k_split<<<8192, 256, 0, stream>>>(resW, B.resWh, nullptr, 6144, 1024, 1024);
    k_wc<<<1536, 256, 0, stream>>>(qkvW, fl1W, fl1b, B.WcF, B.bc);
    k_split<<<1536, 256, 0, stream>>>(B.WcF, B.Wch, nullptr, 384, 1024, 1024);
    k_split<<<256, 256, 0, stream>>>(aW1, B.aW1b, nullptr, 512, 128, 128);
    k_split<<<256, 256, 0, stream>>>(aW2, B.aW2b, nullptr, 128, 512, 512);
    k_split<<<32, 256, 0, stream>>>(pW2, B.pW2b, nullptr, 128, 64, 64);
    k_sk<<<50, 256, 0, stream>>>(fskel, firstW, firstB, B.sk);
    k_gru<<<256, 64, 0, stream>>>(noise, gWih, gWhh, gbih, gbhh, B.aux);

    for (int c = 0; c < nchunks; ++c) {
        long mbase = (long)c * MCr;
        int xb_grid = (int)((MCr * 288 + 255) / 256);
        k_xbuild<<<xb_grid, 256, 0, stream>>>(input + mbase * 256, B.aux + mbase * 10,
                                              B.sk + mbase, B.xh, MCr);
        dim3 gt(8, (unsigned)(MCr / 128));
        k_gemm<0><<<gt, 256, 0, stream>>>(B.xh, B.l0Wh, 1024, 288,
            nullptr, B.actAh, l0b, nullptr, nullptr, nullptr, nullptr, nullptr);
        for (int blk = 0; blk < 3; ++blk) {
            int j0 = blk * 2, j1 = blk * 2 + 1;
            k_gemm<1><<<gt, 256, 0, stream>>>(B.actAh,
                B.resWh + (size_t)j0 * 1024 * 1024,
                1024, 1024, nullptr, B.actBh, resB + j0 * 1024,
                bnG + j0 * 1024, bnB + j0 * 1024, bnM + j0 * 1024, bnV + j0 * 1024,
                nullptr);
            k_gemm<2><<<gt, 256, 0, stream>>>(B.actBh,
                B.resWh + (size_t)j1 * 1024 * 1024,
                1024, 1024, nullptr, B.actAh, resB + j1 * 1024,
                bnG + j1 * 1024, bnB + j1 * 1024, bnM + j1 * 1024, bnV + j1 * 1024,
                B.actAh);
        }
        dim3 gq(3, (unsigned)(MCr / 128));
        k_gemm<0><<<gq, 256, 0, stream>>>(B.actAh, B.Wch, 384, 1024,
            B.qkvF, nullptr, B.bc, nullptr, nullptr, nullptr, nullptr, nullptr);
        k_fl2<<<(int)(MCr / 4), 256, 0, stream>>>(B.actAh, fl2W, fl2b, B.posb);
        k_attn<<<(int)MCr, 256, 0, stream>>>(B.qkvF, B.posb, B.aW1b, B.aW2b, ab1, B.pW2b,
                                             pW1, pb1, pb2, fl3W, fl3b, out, mbase);
    }
}

// Round 9
// 944.069 us; speedup vs baseline: 1.7292x; 1.0807x over previous
//
#include <hip/hip_runtime.h>

typedef __attribute__((ext_vector_type(8))) short bf16x8;
typedef __attribute__((ext_vector_type(4))) float f32x4;
typedef __attribute__((ext_vector_type(4))) ushort u16x4;

// HW bf16 convert (RNE), gfx950 v_cvt_pk_bf16_f32: 2 floats -> 1 VGPR (1 op)
__device__ __forceinline__ unsigned f2b2(float lo, float hi) {
    unsigned r;
    asm("v_cvt_pk_bf16_f32 %0, %1, %2" : "=v"(r) : "v"(lo), "v"(hi));
    return r;
}
__device__ __forceinline__ ushort f2b(float v) {
    return (ushort)f2b2(v, v);
}
__device__ __forceinline__ float b2f(ushort b) {
    union { float f; unsigned u; } x; x.u = ((unsigned)b) << 16; return x.f;
}

// async global->LDS 16B per lane; LDS dest = wave-uniform base + lane*16
__device__ __forceinline__ void gl_lds16(const void* g, void* l) {
    __builtin_amdgcn_global_load_lds(
        (__attribute__((address_space(1))) void*)(g),
        (__attribute__((address_space(3))) void*)(l), 16, 0, 0);
}

// ---------------- prep kernels ----------------

__global__ void k_split(const float* __restrict__ src, ushort* __restrict__ hi,
                        ushort* __restrict__ lo, int rows, int K, int Kpad) {
    long total = (long)rows * Kpad;
    for (long idx = (long)blockIdx.x * 256 + threadIdx.x; idx < total;
         idx += (long)gridDim.x * 256) {
        int r = (int)(idx / Kpad), c = (int)(idx % Kpad);
        float v = (c < K) ? src[(long)r * K + c] : 0.f;
        ushort h = f2b(v);
        hi[idx] = h;
        if (lo) lo[idx] = f2b(v - b2f(h));
    }
}

// Wc[n][k] = sum_d qkvW[n][d] * fl1W[d][k];  bc[n] = sum_d qkvW[n][d] * fl1b[d]
__global__ void k_wc(const float* __restrict__ qkvW, const float* __restrict__ fl1W,
                     const float* __restrict__ fl1b, float* __restrict__ Wc,
                     float* __restrict__ bc) {
    int idx = blockIdx.x * 256 + threadIdx.x;
    if (idx >= 384 * 1024) return;
    int n = idx >> 10, k = idx & 1023;
    float s = 0.f;
    #pragma unroll 8
    for (int d = 0; d < 128; ++d) s += qkvW[n * 128 + d] * fl1W[d * 1024 + k];
    Wc[idx] = s;
    if (k == 0) {
        float sb = 0.f;
        #pragma unroll 8
        for (int d = 0; d < 128; ++d) sb += qkvW[n * 128 + d] * fl1b[d];
        bc[n] = sb;
    }
}

__global__ void k_sk(const float* __restrict__ fs, const float* __restrict__ fW,
                     const float* __restrict__ fb, float* __restrict__ sk) {
    int m = blockIdx.x * 256 + threadIdx.x;
    if (m >= 12800) return;
    int b = m / 50, i = m % 50;
    float s = fb[i];
    #pragma unroll 4
    for (int c = 0; c < 36; ++c) s += fs[b * 36 + c] * fW[i * 36 + c];
    sk[m] = s;
}

// GRU(10->10): one wave (=one block of 64) per batch element -> 256 CUs covered
__global__ void k_gru(const float* __restrict__ noise, const float* __restrict__ Wih,
                      const float* __restrict__ Whh, const float* __restrict__ bih,
                      const float* __restrict__ bhh, float* __restrict__ aux) {
    int lane = threadIdx.x & 63;
    int b = blockIdx.x;
    if (b >= 256) return;
    float wih[10] = {}, whh[10] = {};
    float bi = 0.f, bh = 0.f;
    if (lane < 30) {
        #pragma unroll
        for (int c = 0; c < 10; ++c) { wih[c] = Wih[lane * 10 + c]; whh[c] = Whh[lane * 10 + c]; }
        bi = bih[lane]; bh = bhh[lane];
    }
    float h = 0.f;
    for (int t = 0; t < 50; ++t) {
        float xr = (lane < 10) ? noise[(b * 50 + t) * 10 + lane] : 0.f;
        float gi = bi, gh = bh;
        #pragma unroll
        for (int c = 0; c < 10; ++c) {
            float xc = __shfl(xr, c, 64);
            float hc = __shfl(h, c, 64);
            gi += wih[c] * xc; gh += whh[c] * hc;
        }
        float siz = __shfl(gi, lane + 10, 64), shz = __shfl(gh, lane + 10, 64);
        float sin_ = __shfl(gi, lane + 20, 64), shn = __shfl(gh, lane + 20, 64);
        float r = 1.f / (1.f + expf(-(gi + gh)));
        float z = 1.f / (1.f + expf(-(siz + shz)));
        float n = tanhf(sin_ + r * shn);
        float hn = (1.f - z) * n + z * h;
        if (lane < 10) { h = hn; aux[(b * 50 + t) * 10 + lane] = tanhf(hn); }
    }
}

__global__ void k_xbuild(const float* __restrict__ input, const float* __restrict__ aux,
                         const float* __restrict__ sk, ushort* __restrict__ xhi,
                         long M) {
    long idx = (long)blockIdx.x * 256 + threadIdx.x;
    if (idx >= M * 288) return;
    int m = (int)(idx / 288), c = (int)(idx % 288);
    float v;
    if (c < 256) v = input[(long)m * 256 + c];
    else if (c < 266) v = aux[m * 10 + (c - 256)];
    else if (c == 266) v = sk[m];
    else v = 0.f;
    xhi[idx] = f2b(v);
}

// ---------------- plain-bf16 MFMA GEMM (R13, verified) ----------------
template <int MODE>
__global__ __launch_bounds__(256, 3) void k_gemm(
    const ushort* __restrict__ Ahi,
    const ushort* __restrict__ Bhi,
    int N, int K,
    float* outF, ushort* outHi,
    const float* __restrict__ bias,
    const float* __restrict__ bng, const float* __restrict__ bnb,
    const float* __restrict__ bnm, const float* __restrict__ bnv,
    const ushort* resHi) {
    __shared__ __align__(16) ushort S[2][128][32];   // Ah, Bh : 16 KB
    int t = threadIdx.x;
    // XCD swizzle (bijective m204)
    int flat = blockIdx.y * gridDim.x + blockIdx.x;
    int nwg = gridDim.x * gridDim.y;
    int q = nwg >> 3, r = nwg & 7;
    int xcd = flat & 7, seq = flat >> 3;
    int wgid = (xcd < r ? xcd * (q + 1) : r * (q + 1) + (xcd - r) * q) + seq;
    int bx = wgid % gridDim.x, by = wgid / gridDim.x;
    int m0 = by * 128, n0 = bx * 128;
    int w = t >> 6, lane = t & 63;
    int wm = w >> 1, wn = w & 1;
    int lo16 = lane & 15, hi4 = lane >> 4;

    const int srow = lane >> 2;
    const int skoff = ((lane & 3) ^ (srow & 3)) * 8;   // elements
    const int slot8 = (hi4 ^ (lo16 & 3)) * 8;

    f32x4 acc[4][4];
    #pragma unroll
    for (int i = 0; i < 4; ++i)
        #pragma unroll
        for (int j = 0; j < 4; ++j) acc[i][j] = f32x4{0.f, 0.f, 0.f, 0.f};

    const int nk = K / 32;
    for (int kt = 0; kt < nk; ++kt) {
        const int kb = kt * 32;
        #pragma unroll
        for (int i = 0; i < 2; ++i) {
            int rg = w * 32 + i * 16;              // wave-uniform row-group base
            long ga = (long)(m0 + rg + srow) * K + kb + skoff;
            long gb = (long)(n0 + rg + srow) * K + kb + skoff;
            gl_lds16(&Ahi[ga], &S[0][rg][0]);
            gl_lds16(&Bhi[gb], &S[1][rg][0]);
        }
        __syncthreads();
        bf16x8 ah[4], bh[4];
        #pragma unroll
        for (int m = 0; m < 4; ++m) {
            int row = wm * 64 + m * 16 + lo16;
            ah[m] = *(const bf16x8*)&S[0][row][slot8];
        }
        #pragma unroll
        for (int n = 0; n < 4; ++n) {
            int col = wn * 64 + n * 16 + lo16;
            bh[n] = *(const bf16x8*)&S[1][col][slot8];
        }
        #pragma unroll
        for (int m = 0; m < 4; ++m)
            #pragma unroll
            for (int n = 0; n < 4; ++n)
                acc[m][n] = __builtin_amdgcn_mfma_f32_16x16x32_bf16(ah[m], bh[n], acc[m][n], 0, 0, 0);
        __syncthreads();
    }

    #pragma unroll
    for (int n = 0; n < 4; ++n) {
        int gn = n0 + wn * 64 + n * 16 + lo16;
        float bv = bias ? bias[gn] : 0.f;
        float sc = 1.f, sh = 0.f;
        if (MODE >= 1) { sc = bng[gn] * rsqrtf(bnv[gn] + 1e-5f); sh = bnb[gn] - bnm[gn] * sc; }
        #pragma unroll
        for (int m = 0; m < 4; ++m)
            #pragma unroll
            for (int r2 = 0; r2 < 4; ++r2) {
                int gm = m0 + wm * 64 + m * 16 + hi4 * 4 + r2;
                long o = (long)gm * N + gn;
                float v = acc[m][n][r2] + bv;
                if (MODE >= 1) v = fmaxf(v * sc + sh, 0.f);
                if (MODE == 2) v += b2f(resHi[o]);
                if (outF) outF[o] = v;
                if (outHi) outHi[o] = f2b(v);
            }
    }
}

// ---------------- pos (fl2): wave-per-row, vectorized bf16 act loads ----------------
__global__ void k_fl2(const ushort* __restrict__ hA,
                      const float* __restrict__ W, const float* __restrict__ bias,
                      float* __restrict__ pos) {
    int w = threadIdx.x >> 6, lane = threadIdx.x & 63;
    int m = blockIdx.x * 4 + w;
    float a0 = 0.f, a1 = 0.f, a2 = 0.f;
    for (int k0 = lane * 4; k0 < 1024; k0 += 256) {
        long o = (long)m * 1024 + k0;
        u16x4 hv = *(const u16x4*)&hA[o];
        f32x4 w0 = *(const f32x4*)&W[k0];
        f32x4 w1 = *(const f32x4*)&W[1024 + k0];
        f32x4 w2 = *(const f32x4*)&W[2048 + k0];
        #pragma unroll
        for (int e = 0; e < 4; ++e) {
            float x = b2f(hv[e]);
            a0 += x * w0[e]; a1 += x * w1[e]; a2 += x * w2[e];
        }
    }
    #pragma unroll
    for (int off = 32; off; off >>= 1) {
        a0 += __shfl_xor(a0, off, 64);
        a1 += __shfl_xor(a1, off, 64);
        a2 += __shfl_xor(a2, off, 64);
    }
    if (lane == 0) {
        pos[m * 3 + 0] = a0 + bias[0];
        pos[m * 3 + 1] = a1 + bias[1];
        pos[m * 3 + 2] = a2 + bias[2];
    }
}

// ---------------- k_sim (R14): batched sim MLP over 640k (i,j) rows ----------------
// Row = bi*50 + j (bi = b*50+i). 128 FULLY-VALID rows per block (no 50/64 waste;
// k_attn's old main loop had 22% padded rows and only 16 MFMA/barrier-half).
// Per block: h1[128][64] (VALU) -> rel via MFMA (h1 x pW2^T, phase0b pattern) ->
// X built IN-PLACE over rel in LDS -> e8 loop {GEMM1 8 m-frags/wave, HE LDS,
// GEMM2 partial} -> sim f16 out. 2x MFMA per barrier vs old k_attn.
// LDS (48KB -> 3 blocks/CU):
//   [0,32768)      R: rel then X, [128 rows][256B pitch], swz (d*2)^((row&15)<<4)
//   [32768,49152)  H1 then HE: [128 rows][128B pitch], swz (c*2)^((row&7)<<4)
__global__ __launch_bounds__(256, 3) void k_sim(
    const float* __restrict__ qkv, const float* __restrict__ posb,
    const ushort* __restrict__ W1b, const ushort* __restrict__ W2b,
    const float* __restrict__ b1, const ushort* __restrict__ pW2b,
    const float* __restrict__ pW1, const float* __restrict__ pb1,
    const float* __restrict__ pb2, _Float16* __restrict__ sim) {
    __shared__ __align__(16) char smem[49152];
    // bijective XCD remap
    int flat = blockIdx.x;
    int nwg = gridDim.x;
    int q = nwg >> 3, r = nwg & 7;
    int xcd = flat & 7, seq = flat >> 3;
    int wgid = (xcd < r ? xcd * (q + 1) : r * (q + 1) + (xcd - r) * q) + seq;
    int R0 = wgid * 128;                      // chunk-local row base
    int t = threadIdx.x, w = t >> 6, lane = t & 63;
    int lo16 = lane & 15, hi4 = lane >> 4;
    char* H1 = smem + 32768;

    // ---- phase A: h1[128][64] -> H1 (each thread: one row-half of 32 e) ----
    {
        int rl = t & 127, eh = t >> 7;
        int g = R0 + rl;
        int bi = g / 50, j = g - bi * 50;
        int b = bi / 50;
        int kv = b * 50 + j;
        float d0 = posb[bi * 3] - posb[kv * 3];
        float d1 = posb[bi * 3 + 1] - posb[kv * 3 + 1];
        float d2 = posb[bi * 3 + 2] - posb[kv * 3 + 2];
        int swm = (rl & 7) << 4;
        #pragma unroll
        for (int e0 = 0; e0 < 32; e0 += 2) {
            int e = eh * 32 + e0;
            float v0 = fmaxf(pb1[e] + pW1[e * 3] * d0 + pW1[e * 3 + 1] * d1
                             + pW1[e * 3 + 2] * d2, 0.f);
            float v1 = fmaxf(pb1[e + 1] + pW1[e * 3 + 3] * d0 + pW1[e * 3 + 4] * d1
                             + pW1[e * 3 + 5] * d2, 0.f);
            *(unsigned*)(H1 + rl * 128 + ((e * 2) ^ swm)) = f2b2(v0, v1);
        }
    }
    __syncthreads();

    // ---- phase B: rel = h1 . pW2^T + pb2 -> R (MFMA, 32/wave) ----
    {
        f32x4 racc[8][2];
        #pragma unroll
        for (int m = 0; m < 8; ++m)
            #pragma unroll
            for (int n = 0; n < 2; ++n) racc[m][n] = f32x4{0.f, 0.f, 0.f, 0.f};
        #pragma unroll
        for (int kt = 0; kt < 2; ++kt) {
            int k0 = kt * 32 + hi4 * 8;
            bf16x8 bv[2];
            #pragma unroll
            for (int n = 0; n < 2; ++n)
                bv[n] = *(const bf16x8*)&pW2b[(w * 32 + n * 16 + lo16) * 64 + k0];
            #pragma unroll
            for (int m = 0; m < 8; ++m) {
                int row = m * 16 + lo16;
                bf16x8 ha = *(const bf16x8*)(H1 + row * 128 + ((k0 * 2) ^ ((lo16 & 7) << 4)));
                #pragma unroll
                for (int n = 0; n < 2; ++n)
                    racc[m][n] = __builtin_amdgcn_mfma_f32_16x16x32_bf16(ha, bv[n], racc[m][n], 0, 0, 0);
            }
        }
        #pragma unroll
        for (int m = 0; m < 8; ++m)
            #pragma unroll
            for (int n = 0; n < 2; ++n) {
                int col = w * 32 + n * 16 + lo16;
                float pb = pb2[col];
                #pragma unroll
                for (int rr = 0; rr < 4; ++rr) {
                    int row = m * 16 + hi4 * 4 + rr;
                    *(ushort*)(smem + row * 256 + ((col * 2) ^ ((row & 15) << 4))) =
                        f2b(racc[m][n][rr] + pb);
                }
            }
    }
    __syncthreads();

    // ---- phase C: X = q_i - k_j + rel, IN-PLACE over R ----
    #pragma unroll
    for (int cc = 0; cc < 8; ++cc) {
        int c = cc * 256 + t;
        int row = c >> 4, g16 = c & 15;
        int g = R0 + row;
        int bi = g / 50, j = g - bi * 50;
        int b = bi / 50;
        long kq = (long)bi * 384 + g16 * 8;
        long kk = (long)(b * 50 + j) * 384 + 128 + g16 * 8;
        f32x4 q0 = *(const f32x4*)&qkv[kq];
        f32x4 q1 = *(const f32x4*)&qkv[kq + 4];
        f32x4 k0v = *(const f32x4*)&qkv[kk];
        f32x4 k1v = *(const f32x4*)&qkv[kk + 4];
        char* addr = smem + row * 256 + ((g16 * 16) ^ ((row & 15) << 4));
        bf16x8 rv = *(bf16x8*)addr;
        bf16x8 tv;
        unsigned* tu = (unsigned*)&tv;
        #pragma unroll
        for (int i = 0; i < 2; ++i)
            tu[i] = f2b2(q0[2 * i] - k0v[2 * i] + b2f((ushort)rv[2 * i]),
                         q0[2 * i + 1] - k0v[2 * i + 1] + b2f((ushort)rv[2 * i + 1]));
        #pragma unroll
        for (int i = 0; i < 2; ++i)
            tu[2 + i] = f2b2(q1[2 * i] - k1v[2 * i] + b2f((ushort)rv[4 + 2 * i]),
                             q1[2 * i + 1] - k1v[2 * i + 1] + b2f((ushort)rv[4 + 2 * i + 1]));
        *(bf16x8*)addr = tv;
    }
    __syncthreads();

    // ---- e8 main loop: 2 barriers per e8, 64 MFMA/wave per e8 ----
    f32x4 acc2[8][2];
    #pragma unroll
    for (int m = 0; m < 8; ++m)
        #pragma unroll
        for (int n = 0; n < 2; ++n) acc2[m][n] = f32x4{0.f, 0.f, 0.f, 0.f};

    for (int e8 = 0; e8 < 8; ++e8) {
        // GEMM1: H[:, wave's 16 cols of e8], K=128, 8 m-frags (bv reused 8x)
        f32x4 acc1[8];
        #pragma unroll
        for (int m = 0; m < 8; ++m) acc1[m] = f32x4{0.f, 0.f, 0.f, 0.f};
        __builtin_amdgcn_s_setprio(1);
        #pragma unroll
        for (int kt = 0; kt < 4; ++kt) {
            int col = e8 * 64 + w * 16 + lo16;
            int k0 = kt * 32 + hi4 * 8;
            bf16x8 bfv = *(const bf16x8*)&W1b[(long)col * 128 + k0];
            #pragma unroll
            for (int m = 0; m < 8; ++m) {
                int row = m * 16 + lo16;
                bf16x8 af = *(const bf16x8*)(smem + row * 256 +
                              ((k0 * 2) ^ ((row & 15) << 4)));
                acc1[m] = __builtin_amdgcn_mfma_f32_16x16x32_bf16(af, bfv, acc1[m], 0, 0, 0);
            }
        }
        __builtin_amdgcn_s_setprio(0);
        __syncthreads();   // prev GEMM2 reads of HE done (1st iter: H1 dead)
        {
            int ch = w * 16 + lo16;
            float bb = b1[e8 * 64 + ch];
            #pragma unroll
            for (int m = 0; m < 8; ++m) {
                unsigned p01 = f2b2(fmaxf(acc1[m][0] + bb, 0.f), fmaxf(acc1[m][1] + bb, 0.f));
                unsigned p23 = f2b2(fmaxf(acc1[m][2] + bb, 0.f), fmaxf(acc1[m][3] + bb, 0.f));
                int r0 = m * 16 + hi4 * 4;
                *(ushort*)(H1 + (r0 + 0) * 128 + ((ch * 2) ^ (((r0 + 0) & 7) << 4))) = (ushort)p01;
                *(ushort*)(H1 + (r0 + 1) * 128 + ((ch * 2) ^ (((r0 + 1) & 7) << 4))) = (ushort)(p01 >> 16);
                *(ushort*)(H1 + (r0 + 2) * 128 + ((ch * 2) ^ (((r0 + 2) & 7) << 4))) = (ushort)p23;
                *(ushort*)(H1 + (r0 + 3) * 128 + ((ch * 2) ^ (((r0 + 3) & 7) << 4))) = (ushort)(p23 >> 16);
            }
        }
        __syncthreads();
        // GEMM2 partial: K chunk [e8*64, e8*64+64)
        #pragma unroll
        for (int kt2 = 0; kt2 < 2; ++kt2) {
            int k0 = kt2 * 32 + hi4 * 8;
            bf16x8 af2[8];
            #pragma unroll
            for (int m = 0; m < 8; ++m) {
                int row = m * 16 + lo16;
                af2[m] = *(const bf16x8*)(H1 + row * 128 + ((k0 * 2) ^ ((lo16 & 7) << 4)));
            }
            __builtin_amdgcn_s_setprio(1);
            #pragma unroll
            for (int n = 0; n < 2; ++n) {
                int col = w * 32 + n * 16 + lo16;
                bf16x8 w2 = *(const bf16x8*)&W2b[(long)col * 512 + e8 * 64 + k0];
                #pragma unroll
                for (int m = 0; m < 8; ++m)
                    acc2[m][n] = __builtin_amdgcn_mfma_f32_16x16x32_bf16(af2[m], w2, acc2[m][n], 0, 0, 0);
            }
            __builtin_amdgcn_s_setprio(0);
        }
    }

    // ---- epilogue: sim (f16) ----
    #pragma unroll
    for (int m = 0; m < 8; ++m)
        #pragma unroll
        for (int n = 0; n < 2; ++n) {
            int col = w * 32 + n * 16 + lo16;
            #pragma unroll
            for (int rr = 0; rr < 4; ++rr) {
                int row = m * 16 + hi4 * 4 + rr;
                sim[(long)(R0 + row) * 128 + col] = (_Float16)acc2[m][n][rr];
            }
        }
}

// ---------------- k_soft (R14): per-bi softmax + agg + fl3 ----------------
// = old k_attn minus the GEMM middle: verbatim rel prologue (cheap recompute,
// REL needed for v_ij), sim loaded straight into the acc2 register layout,
// verbatim softmax/agg/fl3 tail. LDS 17.5KB -> high occupancy.
__global__ __launch_bounds__(256, 3) void k_soft(
    const float* __restrict__ qkv, const float* __restrict__ posb,
    const ushort* __restrict__ pW2b,
    const float* __restrict__ pW1, const float* __restrict__ pb1,
    const float* __restrict__ pb2, const _Float16* __restrict__ sim,
    const float* __restrict__ fl3W, const float* __restrict__ fl3b,
    float* __restrict__ out, long mbase) {
    __shared__ __align__(16) char smem[17472];
    int cpx = gridDim.x >> 3;
    int biL = (blockIdx.x & 7) * cpx + (blockIdx.x >> 3);
    int bL = biL / 50;
    int t = threadIdx.x, w = t >> 6, lane = t & 63;
    int lo16 = lane & 15, hi4 = lane >> 4;

    // ---- phase 0a: h1 fragments in registers (row-split, wave-private) ----
    bf16x8 h_a[2];
    {
        const int jrow = w * 16 + lo16;
        const bool jvalid = jrow < 50;
        float pi0 = posb[biL * 3], pi1 = posb[biL * 3 + 1], pi2 = posb[biL * 3 + 2];
        float d0 = 0.f, d1 = 0.f, d2 = 0.f;
        if (jvalid) {
            int pj = (bL * 50 + jrow) * 3;
            d0 = pi0 - posb[pj]; d1 = pi1 - posb[pj + 1]; d2 = pi2 - posb[pj + 2];
        }
        #pragma unroll
        for (int kt = 0; kt < 2; ++kt) {
            float hv[8];
            #pragma unroll
            for (int e = 0; e < 8; ++e) {
                int ke = kt * 32 + hi4 * 8 + e;
                hv[e] = jvalid
                    ? fmaxf(pb1[ke] + pW1[ke * 3] * d0 + pW1[ke * 3 + 1] * d1
                            + pW1[ke * 3 + 2] * d2, 0.f)
                    : 0.f;
            }
            unsigned* hu = (unsigned*)&h_a[kt];
            #pragma unroll
            for (int i = 0; i < 4; ++i) hu[i] = f2b2(hv[2 * i], hv[2 * i + 1]);
        }
    }

    // ---- phase 0b: rel rows for own 16 j (MFMA K=64) -> REL @0 ----
    {
        f32x4 racc[8];
        #pragma unroll
        for (int n = 0; n < 8; ++n) racc[n] = f32x4{0.f, 0.f, 0.f, 0.f};
        #pragma unroll
        for (int kt = 0; kt < 2; ++kt) {
            int k0 = kt * 32 + hi4 * 8;
            #pragma unroll
            for (int n = 0; n < 8; ++n) {
                bf16x8 bv = *(const bf16x8*)&pW2b[(n * 16 + lo16) * 64 + k0];
                racc[n] = __builtin_amdgcn_mfma_f32_16x16x32_bf16(h_a[kt], bv, racc[n], 0, 0, 0);
            }
        }
        int j0 = w * 16 + hi4 * 4;
        #pragma unroll
        for (int n = 0; n < 8; ++n) {
            int col = n * 16 + lo16;
            float pb = pb2[col];
            unsigned p01 = f2b2(racc[n][0] + pb, racc[n][1] + pb);
            unsigned p23 = f2b2(racc[n][2] + pb, racc[n][3] + pb);
            *(ushort*)(smem + (j0 + 0) * 256 + ((col * 2) ^ (((j0 + 0) & 15) << 4))) = (ushort)p01;
            *(ushort*)(smem + (j0 + 1) * 256 + ((col * 2) ^ (((j0 + 1) & 15) << 4))) = (ushort)(p01 >> 16);
            *(ushort*)(smem + (j0 + 2) * 256 + ((col * 2) ^ (((j0 + 2) & 15) << 4))) = (ushort)p23;
            *(ushort*)(smem + (j0 + 3) * 256 + ((col * 2) ^ (((j0 + 3) & 15) << 4))) = (ushort)(p23 >> 16);
        }
    }
    __syncthreads();   // REL complete (agg reads rows written by other waves)

    // ---- load sim into acc2 layout ----
    f32x4 acc2[4][2];
    #pragma unroll
    for (int m = 0; m < 4; ++m)
        #pragma unroll
        for (int n = 0; n < 2; ++n) {
            int col = w * 32 + n * 16 + lo16;
            #pragma unroll
            for (int rr = 0; rr < 4; ++rr) {
                int j = m * 16 + hi4 * 4 + rr;
                acc2[m][n][rr] = (j < 50)
                    ? (float)sim[(long)(biL * 50 + j) * 128 + col] : 0.f;
            }
        }

    // ---- softmax over j + agg (v_ij = v + rel, rel from REL @0) ----
    float outv[2];
    #pragma unroll
    for (int n = 0; n < 2; ++n) {
        float mx = -1e30f;
        #pragma unroll
        for (int m = 0; m < 4; ++m)
            #pragma unroll
            for (int rr = 0; rr < 4; ++rr) {
                int j = m * 16 + hi4 * 4 + rr;
                if (j < 50) mx = fmaxf(mx, acc2[m][n][rr]);
            }
        mx = fmaxf(mx, __shfl_xor(mx, 16, 64));
        mx = fmaxf(mx, __shfl_xor(mx, 32, 64));
        float e[4][4];
        float sum = 0.f;
        #pragma unroll
        for (int m = 0; m < 4; ++m)
            #pragma unroll
            for (int rr = 0; rr < 4; ++rr) {
                int j = m * 16 + hi4 * 4 + rr;
                float ev = (j < 50) ? __expf(acc2[m][n][rr] - mx) : 0.f;
                e[m][rr] = ev; sum += ev;
            }
        sum += __shfl_xor(sum, 16, 64);
        sum += __shfl_xor(sum, 32, 64);
        float inv = 1.f / sum;
        int col = w * 32 + n * 16 + lo16;
        float ag = 0.f;
        #pragma unroll
        for (int m = 0; m < 4; ++m)
            #pragma unroll
            for (int rr = 0; rr < 4; ++rr) {
                int j = m * 16 + hi4 * 4 + rr;
                if (j < 50) {
                    float rl = b2f(*(const ushort*)(smem + j * 256 +
                                  ((col * 2) ^ ((j & 15) << 4))));
                    float vv = qkv[(long)(bL * 50 + j) * 384 + 256 + col] + rl;
                    ag += e[m][rr] * inv * vv;
                }
            }
        ag += __shfl_xor(ag, 16, 64);
        ag += __shfl_xor(ag, 32, 64);
        outv[n] = ag;
    }
    float* aggF = (float*)(smem + 16384);
    float* part = (float*)(smem + 16896);   // f32[4][36]
    if (hi4 == 0) {
        aggF[w * 32 + lo16] = outv[0];
        aggF[w * 32 + 16 + lo16] = outv[1];
    }
    // fl3 partials: wave-local read of OWN aggF slice (same-wave DS ordering)
    if (lane < 36) {
        const float* wf = &fl3W[lane * 128 + w * 32];
        const float* af = aggF + w * 32;
        float s = 0.f;
        #pragma unroll 8
        for (int d = 0; d < 32; ++d) s += af[d] * wf[d];
        part[w * 36 + lane] = s;
    }
    __syncthreads();

    if (t < 36) {
        float s = fl3b[t] + part[t] + part[36 + t] + part[72 + t] + part[108 + t];
        out[(mbase + biL) * 36 + t] = tanhf(s);
    }
}

// ---------------- launch ----------------
struct Bufs {
    float *sk, *aux, *qkvF, *posb, *WcF, *bc;
    ushort *xh, *actAh, *actBh;
    ushort *l0Wh, *resWh, *Wch, *aW1b, *aW2b, *pW2b;
    ushort *sim;   // _Float16 storage
};

static size_t plan_ws(char* ws, long MCr, Bufs& B) {
    size_t off = 0;
    auto alloc = [&](size_t n) { char* p = ws + off; off += (n + 255) & ~(size_t)255; return p; };
    B.sk    = (float*) alloc(12800L * 4);
    B.aux   = (float*) alloc(128000L * 4);
    B.xh    = (ushort*)alloc((size_t)MCr * 288 * 2);
    B.actAh = (ushort*)alloc((size_t)MCr * 1024 * 2);
    B.actBh = (ushort*)alloc((size_t)MCr * 1024 * 2);
    B.qkvF  = (float*) alloc((size_t)MCr * 384 * 4);
    B.posb  = (float*) alloc((size_t)MCr * 3 * 4);
    B.sim   = (ushort*)alloc((size_t)MCr * 50 * 128 * 2);
    B.l0Wh  = (ushort*)alloc(1024L * 288 * 2);
    B.resWh = (ushort*)alloc(6144L * 1024 * 2);
    B.WcF   = (float*) alloc(384L * 1024 * 4);
    B.Wch   = (ushort*)alloc(384L * 1024 * 2);
    B.bc    = (float*) alloc(384L * 4);
    B.aW1b  = (ushort*)alloc(512L * 128 * 2);
    B.aW2b  = (ushort*)alloc(128L * 512 * 2);
    B.pW2b  = (ushort*)alloc(128L * 64 * 2);
    return off;
}

extern "C" void kernel_launch(void* const* d_in, const int* in_sizes, int n_in,
                              void* d_out, int out_size, void* d_ws, size_t ws_size,
                              hipStream_t stream) {
    (void)in_sizes; (void)n_in;
    const float* input  = (const float*)d_in[0];
    const float* fskel  = (const float*)d_in[1];
    const float* noise  = (const float*)d_in[2];
    const float* firstW = (const float*)d_in[3];
    const float* firstB = (const float*)d_in[4];
    const float* gWih   = (const float*)d_in[5];
    const float* gWhh   = (const float*)d_in[6];
    const float* gbih   = (const float*)d_in[7];
    const float* gbhh   = (const float*)d_in[8];
    const float* l0W    = (const float*)d_in[9];
    const float* l0b    = (const float*)d_in[10];
    const float* resW   = (const float*)d_in[11];
    const float* resB   = (const float*)d_in[12];
    const float* bnG    = (const float*)d_in[13];
    const float* bnB    = (const float*)d_in[14];
    const float* bnM    = (const float*)d_in[15];
    const float* bnV    = (const float*)d_in[16];
    const float* fl1W   = (const float*)d_in[17];
    const float* fl1b   = (const float*)d_in[18];
    const float* fl2W   = (const float*)d_in[19];
    const float* fl2b   = (const float*)d_in[20];
    const float* fl3W   = (const float*)d_in[21];
    const float* fl3b   = (const float*)d_in[22];
    const float* qkvW   = (const float*)d_in[23];
    const float* pW1    = (const float*)d_in[24];
    const float* pb1    = (const float*)d_in[25];
    const float* pW2    = (const float*)d_in[26];
    const float* pb2    = (const float*)d_in[27];
    const float* aW1    = (const float*)d_in[28];
    const float* ab1    = (const float*)d_in[29];
    const float* aW2    = (const float*)d_in[30];
    float* out = (float*)d_out;

    char* ws = (char*)d_ws;
    Bufs B;
    long MCr = 12800;
    while (plan_ws(ws, MCr, B) > ws_size) {
        MCr >>= 1;                                 // 6400, 3200, 1600 (all %50==0)
        if (MCr < 1600) {                          // diagnostic: clean zero output
            hipMemsetAsync(d_out, 0, (size_t)out_size * sizeof(float), stream);
            return;
        }
    }
    const int nchunks = (int)(12800 / MCr);

    // one-time prep
    k_split<<<1152, 256, 0, stream>>>(l0W, B.l0Wh, nullptr, 1024, 267, 288);
    k_split<<<8192, 256, 0, stream>>>(resW, B.resWh, nullptr, 6144, 1024, 1024);
    k_wc<<<1536, 256, 0, stream>>>(qkvW, fl1W, fl1b, B.WcF, B.bc);
    k_split<<<1536, 256, 0, stream>>>(B.WcF, B.Wch, nullptr, 384, 1024, 1024);
    k_split<<<256, 256, 0, stream>>>(aW1, B.aW1b, nullptr, 512, 128, 128);
    k_split<<<256, 256, 0, stream>>>(aW2, B.aW2b, nullptr, 128, 512, 512);
    k_split<<<32, 256, 0, stream>>>(pW2, B.pW2b, nullptr, 128, 64, 64);
    k_sk<<<50, 256, 0, stream>>>(fskel, firstW, firstB, B.sk);
    k_gru<<<256, 64, 0, stream>>>(noise, gWih, gWhh, gbih, gbhh, B.aux);

    for (int c = 0; c < nchunks; ++c) {
        long mbase = (long)c * MCr;
        int xb_grid = (int)((MCr * 288 + 255) / 256);
        k_xbuild<<<xb_grid, 256, 0, stream>>>(input + mbase * 256, B.aux + mbase * 10,
                                              B.sk + mbase, B.xh, MCr);
        dim3 gt(8, (unsigned)(MCr / 128));
        k_gemm<0><<<gt, 256, 0, stream>>>(B.xh, B.l0Wh, 1024, 288,
            nullptr, B.actAh, l0b, nullptr, nullptr, nullptr, nullptr, nullptr);
        for (int blk = 0; blk < 3; ++blk) {
            int j0 = blk * 2, j1 = blk * 2 + 1;
            k_gemm<1><<<gt, 256, 0, stream>>>(B.actAh,
                B.resWh + (size_t)j0 * 1024 * 1024,
                1024, 1024, nullptr, B.actBh, resB + j0 * 1024,
                bnG + j0 * 1024, bnB + j0 * 1024, bnM + j0 * 1024, bnV + j0 * 1024,
                nullptr);
            k_gemm<2><<<gt, 256, 0, stream>>>(B.actBh,
                B.resWh + (size_t)j1 * 1024 * 1024,
                1024, 1024, nullptr, B.actAh, resB + j1 * 1024,
                bnG + j1 * 1024, bnB + j1 * 1024, bnM + j1 * 1024, bnV + j1 * 1024,
                B.actAh);
        }
        dim3 gq(3, (unsigned)(MCr / 128));
        k_gemm<0><<<gq, 256, 0, stream>>>(B.actAh, B.Wch, 384, 1024,
            B.qkvF, nullptr, B.bc, nullptr, nullptr, nullptr, nullptr, nullptr);
        k_fl2<<<(int)(MCr / 4), 256, 0, stream>>>(B.actAh, fl2W, fl2b, B.posb);
        int nsim = (int)(MCr * 50 / 128);
        k_sim<<<nsim, 256, 0, stream>>>(B.qkvF, B.posb, B.aW1b, B.aW2b, ab1, B.pW2b,
                                        pW1, pb1, pb2, (_Float16*)B.sim);
        k_soft<<<(int)MCr, 256, 0, stream>>>(B.qkvF, B.posb, B.pW2b, pW1, pb1, pb2,
                                             (const _Float16*)B.sim, fl3W, fl3b,
                                             out, mbase);
    }
}